// Round 8
// baseline (631.033 us; speedup 1.0000x reference)
//
#include <hip/hip_runtime.h>

typedef unsigned short u16;
typedef __attribute__((ext_vector_type(8))) short bf16x8v;
typedef __attribute__((ext_vector_type(4))) float f32x4v;

#define B_SZ 16384
#define F_SZ 50
#define E_SZ 64
#define D_SZ 512
#define H1_SZ 1024
#define H2_SZ 512
#define KP 4096   // padded product-layer K: (e*64+f), f padded 50->64

__device__ __forceinline__ float b2f(u16 u){
  union { unsigned int i; float f; } v; v.i = ((unsigned int)u) << 16; return v.f;
}
__device__ __forceinline__ u16 f2b(float f){
  union { float f; unsigned int i; } v; v.f = f;
  unsigned int r = v.i + 0x7FFFu + ((v.i >> 16) & 1u);
  return (u16)(r >> 16);
}

// async global->LDS, 16B/lane. g is per-lane (base + lane*16B); lds base is
// wave-uniform; HW writes lds_base + lane*16.
__device__ __forceinline__ void gload16(const u16* g, u16* lds_base_uniform){
#if __has_builtin(__builtin_amdgcn_global_load_lds)
  __builtin_amdgcn_global_load_lds(
      (const __attribute__((address_space(1))) unsigned int*)g,
      (__attribute__((address_space(3))) unsigned int*)lds_base_uniform,
      16, 0, 0);
#else
  int lane = threadIdx.x & 63;
  *(uint4*)(lds_base_uniform + lane*8) = *(const uint4*)g;
#endif
}

// ---------------- gather: embT[b][e*64+f] = fe[idx[b,f],e]*fv[b,f] (bf16), f>=50 -> 0
__global__ __launch_bounds__(256) void k_gather(
    const int* __restrict__ fidx, const float* __restrict__ fval,
    const float* __restrict__ femb, u16* __restrict__ embT)
{
  __shared__ int   sidx[F_SZ];
  __shared__ float sfv[F_SZ];
  __shared__ u16   tile[F_SZ*66];   // padded stride 66 to break bank conflicts
  const int b = blockIdx.x, t = threadIdx.x;
  if (t < F_SZ){ sidx[t] = fidx[b*F_SZ+t]; sfv[t] = fval[b*F_SZ+t]; }
  __syncthreads();
  #pragma unroll
  for (int i=0;i<13;i++){
    int k = i*256+t;
    if (k < F_SZ*E_SZ){
      int f = k>>6, e = k&63;
      tile[f*66+e] = f2b(femb[(size_t)sidx[f]*E_SZ + e] * sfv[f]);
    }
  }
  __syncthreads();
  u16* orow = embT + (size_t)b*KP;
  #pragma unroll
  for (int i=0;i<16;i++){
    int k = i*256+t;           // k = e*64+f
    int f = k&63, e = k>>6;
    orow[k] = (f < F_SZ) ? tile[f*66+e] : (u16)0;
  }
}

// ---------------- product_linear (D,F,E) fp32 -> WlT (D, e*64+f) bf16 zero-padded
__global__ __launch_bounds__(256) void k_wlt(const float* __restrict__ Wl, u16* __restrict__ WlT)
{
  __shared__ u16 tile[F_SZ*66];
  const int d = blockIdx.x, t = threadIdx.x;
  #pragma unroll
  for (int i=0;i<13;i++){
    int k = i*256+t;
    if (k < F_SZ*E_SZ) tile[(k>>6)*66 + (k&63)] = f2b(Wl[(size_t)d*(F_SZ*E_SZ) + k]);
  }
  __syncthreads();
  u16* orow = WlT + (size_t)d*KP;
  #pragma unroll
  for (int i=0;i<16;i++){
    int k = i*256+t;
    int f = k&63, e = k>>6;
    orow[k] = (f < F_SZ) ? tile[f*66+e] : (u16)0;
  }
}

// ---------------- product_quadratic_inner (D,F) fp32 -> PqTp (D,64) bf16 padded
__global__ void k_pqt(const float* __restrict__ Pq, u16* __restrict__ PqTp){
  int idx = blockIdx.x*256 + threadIdx.x;   // grid 128 -> 32768
  int d = idx >> 6, f = idx & 63;
  PqTp[idx] = (f < F_SZ) ? f2b(Pq[d*F_SZ + f]) : (u16)0;
}

// ---------------- (K,N) fp32 -> (N,K) bf16 transpose for dense weights
__global__ void k_transpose(const float* __restrict__ W, u16* __restrict__ WT,
                            int klog2, int N, int total){
  int idx = blockIdx.x*256 + threadIdx.x;
  if (idx < total){
    int k = idx & ((1<<klog2)-1), n = idx >> klog2;
    WT[idx] = f2b(W[(size_t)k*N + n]);
  }
}

// ---------------- cvec[h] += sum_{d in chunk} pbias[d]*W0[d][h] (+ b0[h] once)
__global__ __launch_bounds__(256) void k_cvec(
    const float* __restrict__ pb, const float* __restrict__ W0,
    const float* __restrict__ b0, float* __restrict__ cvec)
{
  int h = blockIdx.x*256 + threadIdx.x;
  int d0 = blockIdx.y*64;
  float acc = (blockIdx.y == 0) ? b0[h] : 0.f;
  #pragma unroll 8
  for (int d=0; d<64; d++) acc += pb[d0+d]*W0[(size_t)(d0+d)*H1_SZ + h];
  atomicAdd(&cvec[h], acc);
}

// ---------------- fused product layer, v3: LDS-FREE, barrier-free.
// 512 threads, 128b x 128d block tile; wave = 32m x 64n (acc+lpa = 64 accum).
// A (embT) and B (WlT) fragments loaded per-lane (16B) straight from global:
// WlT is 4 MB -> L2-resident; redundant wr-wave B reads are L1-served; embT
// streams from HBM with one-chunk-ahead ping-pong prefetch. No __syncthreads,
// no vmcnt(0) drains, no LDS bank conflicts -- waves pipeline independently.
// Pq fragments (pfr) are loop-invariant in registers.
// Epilogue: y0 = relu(lz + sqrt(lp) + pbias) - pbias   (bias-centered bf16).
__global__ __launch_bounds__(512) void k_prod(
    const u16* __restrict__ A,     // embT (B, KP)
    const u16* __restrict__ Bm,    // WlT  (D, KP)
    const u16* __restrict__ Pp,    // PqTp (D, 64)
    const float* __restrict__ pbias,
    u16* __restrict__ y0)          // (B, D)
{
  const int tid  = threadIdx.x;
  const int wave = tid >> 6, lane = tid & 63;
  const int quad = lane >> 4, l16 = lane & 15;
  const int n0 = blockIdx.x * 128, m0 = blockIdx.y * 128;
  const int wr = wave >> 1, wc = wave & 1;   // wr 0..3 (32 m-rows), wc 0..1 (64 n)

  // loop-invariant P fragments: rows = d, k = f
  bf16x8v pfr[4][2];
  #pragma unroll
  for (int nt=0;nt<4;nt++)
    #pragma unroll
    for (int ks=0;ks<2;ks++)
      pfr[nt][ks] = *(const bf16x8v*)&Pp[(n0 + wc*64 + nt*16 + l16)*64 + ks*32 + quad*8];

  // per-lane row base pointers (fragment element k0 + ks*32 + quad*8)
  const u16* aP0 = A  + (size_t)(m0 + wr*32      + l16)*KP + quad*8;
  const u16* aP1 = aP0 + (size_t)16*KP;
  const u16* bP0 = Bm + (size_t)(n0 + wc*64      + l16)*KP + quad*8;
  const u16* bP1 = bP0 + (size_t)16*KP;
  const u16* bP2 = bP0 + (size_t)32*KP;
  const u16* bP3 = bP0 + (size_t)48*KP;

  f32x4v acc[2][4];   // lz accumulator
  f32x4v lpa[2][4];   // sum over e of S_e^2
  #pragma unroll
  for (int i=0;i<2;i++)
    #pragma unroll
    for (int j=0;j<4;j++){
      acc[i][j] = (f32x4v){0.f,0.f,0.f,0.f};
      lpa[i][j] = (f32x4v){0.f,0.f,0.f,0.f};
    }
  const f32x4v zz = {0.f,0.f,0.f,0.f};

  bf16x8v afA[4], bfA[8], afB[4], bfB[8];   // [ks*2+mt], [ks*4+nt]

#define PROD_LOAD(AF, BF, OFF)                                          \
  {                                                                     \
    const size_t o_ = (OFF);                                            \
    AF[0] = *(const bf16x8v*)(aP0 + o_);                                \
    AF[1] = *(const bf16x8v*)(aP1 + o_);                                \
    AF[2] = *(const bf16x8v*)(aP0 + o_ + 32);                           \
    AF[3] = *(const bf16x8v*)(aP1 + o_ + 32);                           \
    BF[0] = *(const bf16x8v*)(bP0 + o_);                                \
    BF[1] = *(const bf16x8v*)(bP1 + o_);                                \
    BF[2] = *(const bf16x8v*)(bP2 + o_);                                \
    BF[3] = *(const bf16x8v*)(bP3 + o_);                                \
    BF[4] = *(const bf16x8v*)(bP0 + o_ + 32);                           \
    BF[5] = *(const bf16x8v*)(bP1 + o_ + 32);                           \
    BF[6] = *(const bf16x8v*)(bP2 + o_ + 32);                           \
    BF[7] = *(const bf16x8v*)(bP3 + o_ + 32);                           \
  }

#define PROD_STEP(AF, BF)                                               \
  {                                                                     \
    _Pragma("unroll")                                                   \
    for (int ks=0; ks<2; ks++)                                          \
      _Pragma("unroll")                                                 \
      for (int mt=0; mt<2; mt++)                                        \
        _Pragma("unroll")                                               \
        for (int nt=0; nt<4; nt++)                                      \
          acc[mt][nt] = __builtin_amdgcn_mfma_f32_16x16x32_bf16(        \
              AF[ks*2+mt], BF[ks*4+nt], acc[mt][nt], 0, 0, 0);          \
    _Pragma("unroll")                                                   \
    for (int nt=0; nt<4; nt++){                                         \
      f32x4v s0 = __builtin_amdgcn_mfma_f32_16x16x32_bf16(              \
              AF[0], pfr[nt][0], zz, 0, 0, 0);                          \
      f32x4v s1 = __builtin_amdgcn_mfma_f32_16x16x32_bf16(              \
              AF[1], pfr[nt][0], zz, 0, 0, 0);                          \
      s0 = __builtin_amdgcn_mfma_f32_16x16x32_bf16(                     \
              AF[2], pfr[nt][1], s0, 0, 0, 0);                          \
      s1 = __builtin_amdgcn_mfma_f32_16x16x32_bf16(                     \
              AF[3], pfr[nt][1], s1, 0, 0, 0);                          \
      _Pragma("unroll")                                                 \
      for (int r=0; r<4; r++){                                          \
        lpa[0][nt][r] = fmaf(s0[r], s0[r], lpa[0][nt][r]);              \
        lpa[1][nt][r] = fmaf(s1[r], s1[r], lpa[1][nt][r]);              \
      }                                                                 \
    }                                                                   \
  }

  PROD_LOAD(afA, bfA, 0)
  #pragma unroll 1
  for (int c=0; c<64; c+=2){
    // prefetch chunk c+1 while computing c
    PROD_LOAD(afB, bfB, (size_t)(c+1)*64)
    PROD_STEP(afA, bfA)
    // prefetch chunk c+2 (at c=62 this overshoots 8 KB into mapped ws; unused)
    PROD_LOAD(afA, bfA, (size_t)(c+2)*64)
    PROD_STEP(afB, bfB)
  }
#undef PROD_LOAD
#undef PROD_STEP

  // epilogue; C/D layout: n = lane&15, m = quad*4 + reg
  #pragma unroll
  for (int nt=0;nt<4;nt++){
    const int n = n0 + wc*64 + nt*16 + l16;
    const float bv = pbias[n];
    #pragma unroll
    for (int mt=0;mt<2;mt++){
      const int mb = m0 + wr*32 + mt*16 + quad*4;
      #pragma unroll
      for (int r=0;r<4;r++){
        float v = acc[mt][nt][r] + sqrtf(lpa[mt][nt][r]) + bv;
        v = (v > 0.f ? v : 0.f) - bv;
        y0[(size_t)(mb+r)*D_SZ + n] = f2b(v);
      }
    }
  }
}

// ---------------- m97-style BT GEMM: C(MxN) = A(MxK) * Bm(NxK)^T, bf16 inputs
// DO_STATS: add fp32 bias[n], atomically accumulate per-column sum/sumsq.
template<int DO_STATS, typename CT>
__global__ __launch_bounds__(256) void gemm_bt(
    const u16* __restrict__ A, const u16* __restrict__ Bm,
    CT* __restrict__ C, const float* __restrict__ bias,
    float* __restrict__ S1, float* __restrict__ S2,
    int M, int N, int K)
{
  __shared__ __align__(16) u16 As[128*64];
  __shared__ __align__(16) u16 Bs[128*64];
  const int tid  = threadIdx.x;
  const int wave = tid >> 6, lane = tid & 63;
  const int quad = lane >> 4, l16 = lane & 15;
  const int n0 = blockIdx.x * 128, m0 = blockIdx.y * 128;
  const int wr = wave >> 1, wc = wave & 1;
  const int lr = lane >> 3, lc = (lane & 7) * 8;

  f32x4v acc[4][4];
  #pragma unroll
  for (int i=0;i<4;i++)
    #pragma unroll
    for (int j=0;j<4;j++)
      acc[i][j] = (f32x4v){0.f,0.f,0.f,0.f};

  for (int k0 = 0; k0 < K; k0 += 64){
    __syncthreads();
    #pragma unroll
    for (int c=0;c<4;c++){
      const int r0 = wave*32 + 8*c;          // 8 rows per 16B-call
      gload16(A  + (size_t)(m0 + r0 + lr)*K + k0 + lc, As + r0*64);
      gload16(Bm + (size_t)(n0 + r0 + lr)*K + k0 + lc, Bs + r0*64);
    }
    __syncthreads();
    #pragma unroll
    for (int ks=0; ks<2; ks++){
      bf16x8v af[4], bfr[4];
      #pragma unroll
      for (int mt=0;mt<4;mt++)
        af[mt] = *(const bf16x8v*)&As[(wr*64+mt*16+l16)*64 + ks*32 + quad*8];
      #pragma unroll
      for (int nt=0;nt<4;nt++)
        bfr[nt] = *(const bf16x8v*)&Bs[(wc*64+nt*16+l16)*64 + ks*32 + quad*8];
      #pragma unroll
      for (int mt=0;mt<4;mt++)
        #pragma unroll
        for (int nt=0;nt<4;nt++)
          acc[mt][nt] = __builtin_amdgcn_mfma_f32_16x16x32_bf16(af[mt], bfr[nt], acc[mt][nt], 0, 0, 0);
    }
  }

  // epilogue; C/D layout: n = lane&15, m = quad*4 + reg
  #pragma unroll
  for (int nt=0;nt<4;nt++){
    const int n = n0 + wc*64 + nt*16 + l16;
    float bv = 0.f;
    if (DO_STATS) bv = bias[n];
    float ls1 = 0.f, ls2 = 0.f;
    #pragma unroll
    for (int mt=0;mt<4;mt++){
      const int mb = m0 + wr*64 + mt*16 + quad*4;
      #pragma unroll
      for (int r=0;r<4;r++){
        float v = acc[mt][nt][r] + bv;
        if constexpr (sizeof(CT) == 2) C[(size_t)(mb+r)*N + n] = f2b(v);
        else                           C[(size_t)(mb+r)*N + n] = v;
        ls1 += v; ls2 += v*v;
      }
    }
    if (DO_STATS){
      ls1 += __shfl_xor(ls1, 16); ls2 += __shfl_xor(ls2, 16);
      ls1 += __shfl_xor(ls1, 32); ls2 += __shfl_xor(ls2, 32);
      if (quad == 0){ atomicAdd(&S1[n], ls1); atomicAdd(&S2[n], ls2); }
    }
  }
}

// ---------------- BN finalize: per-column scale/offset from sums
__global__ void k_bnfin(const float* __restrict__ S1, const float* __restrict__ S2, int n,
                        const float* __restrict__ bnsc, const float* __restrict__ bnof,
                        float* __restrict__ Aout, float* __restrict__ Bout)
{
  int i = blockIdx.x*256 + threadIdx.x;
  if (i < n){
    const float invB = 1.f / 16384.f;
    float m   = S1[i]*invB;
    float var = S2[i]*invB - m*m;
    float a   = bnsc[0] * rsqrtf(var + 1e-10f);
    Aout[i] = a;
    Bout[i] = bnof[0] - m*a;
  }
}

// ---------------- BN apply + relu: fp32 Z in, bf16 Y out, 8 elems/thread
__global__ __launch_bounds__(256) void k_bnapply(
    const float* __restrict__ Z, u16* __restrict__ Y,
    const float* __restrict__ Aa, const float* __restrict__ Bb, int nmask)
{
  size_t base = ((size_t)blockIdx.x*256 + threadIdx.x) * 8;
  int n0 = (int)(base & (size_t)nmask);
  float4 za = *(const float4*)&Z[base];
  float4 zb = *(const float4*)&Z[base+4];
  float zz[8] = {za.x,za.y,za.z,za.w,zb.x,zb.y,zb.z,zb.w};
  union { uint4 q; u16 s[8]; } o;
  #pragma unroll
  for (int j=0;j<8;j++){
    float v = zz[j] * Aa[n0+j] + Bb[n0+j];
    o.s[j] = f2b(v > 0.f ? v : 0.f);
  }
  *(uint4*)&Y[base] = o.q;
}

// ---------------- final dot + sigmoid, one wave per row; fp32 w and out
__global__ __launch_bounds__(256) void k_out(
    const u16* __restrict__ Y2, const float* __restrict__ wvec,
    const float* __restrict__ obp, float* __restrict__ out)
{
  const int wave = threadIdx.x >> 6, lane = threadIdx.x & 63;
  const int b = blockIdx.x*4 + wave;
  union { uint4 q; u16 s[8]; } y;
  y.q = *(const uint4*)&Y2[(size_t)b*H2_SZ + lane*8];
  float4 wa = *(const float4*)&wvec[lane*8];
  float4 wb = *(const float4*)&wvec[lane*8+4];
  float wv[8] = {wa.x,wa.y,wa.z,wa.w,wb.x,wb.y,wb.z,wb.w};
  float s = 0.f;
  #pragma unroll
  for (int j=0;j<8;j++) s += b2f(y.s[j]) * wv[j];
  s += __shfl_xor(s,1);  s += __shfl_xor(s,2);  s += __shfl_xor(s,4);
  s += __shfl_xor(s,8);  s += __shfl_xor(s,16); s += __shfl_xor(s,32);
  if (lane == 0){
    float x = s + obp[0];
    out[b] = 1.f / (1.f + expf(-x));
  }
}

// ---------------- workspace map (bytes) ----------------
// embT @ 0          : 134217728   (dead after k_prod; reused:)
//   z1 @ 0          :  67108864   (fp32 pre-BN layer0)
//   y1 @ 67108864   :  33554432   (bf16 post-BN layer0)
//   z2 @ 100663296  :  33554432   (fp32 pre-BN layer1)
// WlT  @ 134217728  :   4194304   (dead after k_prod; +8KB prefetch overshoot ok)
// y0   @ 138412032  :  16777216   (bf16, bias-centered)
// W0T  @ 155189248  :   1048576
// W1T  @ 156237824  :   1048576
// y2   @ 157286400  :  16777216   (bf16 post-BN layer1)
// stats@ 174063616  : 16 KB ZEROED: S1a[1024] S2a[1024] S1b[512] S2b[512] cvec[1024]
//                     then A0[1024] B0[1024] A1[512] B1[512]
// pqT  @ 174096384  :     65536
// total ~ 174.2 MB

extern "C" void kernel_launch(void* const* d_in, const int* in_sizes, int n_in,
                              void* d_out, int out_size, void* d_ws, size_t ws_size,
                              hipStream_t stream)
{
  const int*   fidx  = (const int*)d_in[0];
  const float* fval  = (const float*)d_in[1];
  const float* femb  = (const float*)d_in[2];
  const float* wl    = (const float*)d_in[3];
  const float* pbias = (const float*)d_in[4];
  const float* pq    = (const float*)d_in[5];
  const float* w0    = (const float*)d_in[6];
  const float* b0    = (const float*)d_in[7];
  const float* w1    = (const float*)d_in[8];
  const float* b1    = (const float*)d_in[9];
  const float* bnsc  = (const float*)d_in[10];
  const float* bnof  = (const float*)d_in[11];
  const float* ow    = (const float*)d_in[12];
  const float* ob    = (const float*)d_in[13];
  float* out = (float*)d_out;

  char* ws = (char*)d_ws;
  u16*   embT = (u16*)(ws + 0);
  float* z1b  = (float*)(ws + 0);
  u16*   y1b  = (u16*)(ws + 67108864);
  float* z2b  = (float*)(ws + 100663296);
  u16*   wlT  = (u16*)(ws + 134217728);
  u16*   y0b  = (u16*)(ws + 138412032);
  u16*   w0T  = (u16*)(ws + 155189248);
  u16*   w1T  = (u16*)(ws + 156237824);
  u16*   y2b  = (u16*)(ws + 157286400);
  float* S1a  = (float*)(ws + 174063616);
  float* S2a  = S1a + 1024;
  float* S1b  = S2a + 1024;
  float* S2b  = S1b + 512;
  float* cvec = S2b + 512;
  float* A0   = cvec + 1024;
  float* B0   = A0 + 1024;
  float* A1   = B0 + 1024;
  float* B1   = A1 + 512;
  u16*   pqT  = (u16*)(ws + 174096384);

  hipMemsetAsync((void*)S1a, 0, 16384, stream);      // S1a,S2a,S1b,S2b,cvec

  k_gather<<<B_SZ, 256, 0, stream>>>(fidx, fval, femb, embT);
  k_wlt<<<D_SZ, 256, 0, stream>>>(wl, wlT);
  k_pqt<<<128, 256, 0, stream>>>(pq, pqT);
  k_transpose<<<2048, 256, 0, stream>>>(w0, w0T, 9, 1024, 524288);   // (512,1024)->(1024,512)
  k_transpose<<<2048, 256, 0, stream>>>(w1, w1T, 10, 512, 524288);   // (1024,512)->(512,1024)
  k_cvec<<<dim3(4,8), 256, 0, stream>>>(pbias, w0, b0, cvec);

  k_prod<<<dim3(4,128), 512, 0, stream>>>(embT, wlT, pqT, pbias, y0b);

  gemm_bt<1,float><<<dim3(8,128), 256, 0, stream>>>(y0b, w0T, z1b, cvec, S1a, S2a,
                                                    B_SZ, H1_SZ, D_SZ);
  k_bnfin<<<4, 256, 0, stream>>>(S1a, S2a, 1024, bnsc, bnof, A0, B0);
  k_bnapply<<<8192, 256, 0, stream>>>(z1b, y1b, A0, B0, 1023);

  gemm_bt<1,float><<<dim3(4,128), 256, 0, stream>>>(y1b, w1T, z2b, b1, S1b, S2b,
                                                    B_SZ, H2_SZ, H1_SZ);
  k_bnfin<<<2, 256, 0, stream>>>(S1b, S2b, 512, bnsc, bnof, A1, B1);
  k_bnapply<<<4096, 256, 0, stream>>>(z2b, y2b, A1, B1, 511);

  k_out<<<4096, 256, 0, stream>>>(y2b, ow, ob, out);
}

// Round 9
// 443.271 us; speedup vs baseline: 1.4236x; 1.4236x over previous
//
#include <hip/hip_runtime.h>

typedef unsigned short u16;
typedef __attribute__((ext_vector_type(8))) short bf16x8v;
typedef __attribute__((ext_vector_type(4))) float f32x4v;

#define B_SZ 16384
#define F_SZ 50
#define E_SZ 64
#define D_SZ 512
#define H1_SZ 1024
#define H2_SZ 512
#define KP 4096   // padded product-layer K: (e*64+f), f padded 50->64

__device__ __forceinline__ float b2f(u16 u){
  union { unsigned int i; float f; } v; v.i = ((unsigned int)u) << 16; return v.f;
}
__device__ __forceinline__ u16 f2b(float f){
  union { float f; unsigned int i; } v; v.f = f;
  unsigned int r = v.i + 0x7FFFu + ((v.i >> 16) & 1u);
  return (u16)(r >> 16);
}

// async global->LDS, 16B/lane. g is per-lane (base + lane*16B); lds base is
// wave-uniform; HW writes lds_base + lane*16.
__device__ __forceinline__ void gload16(const u16* g, u16* lds_base_uniform){
#if __has_builtin(__builtin_amdgcn_global_load_lds)
  __builtin_amdgcn_global_load_lds(
      (const __attribute__((address_space(1))) unsigned int*)g,
      (__attribute__((address_space(3))) unsigned int*)lds_base_uniform,
      16, 0, 0);
#else
  int lane = threadIdx.x & 63;
  *(uint4*)(lds_base_uniform + lane*8) = *(const uint4*)g;
#endif
}

// ---------------- gather: embT[b][e*64+f] = fe[idx[b,f],e]*fv[b,f] (bf16), f>=50 -> 0
__global__ __launch_bounds__(256) void k_gather(
    const int* __restrict__ fidx, const float* __restrict__ fval,
    const float* __restrict__ femb, u16* __restrict__ embT)
{
  __shared__ int   sidx[F_SZ];
  __shared__ float sfv[F_SZ];
  __shared__ u16   tile[F_SZ*66];   // padded stride 66 to break bank conflicts
  const int b = blockIdx.x, t = threadIdx.x;
  if (t < F_SZ){ sidx[t] = fidx[b*F_SZ+t]; sfv[t] = fval[b*F_SZ+t]; }
  __syncthreads();
  #pragma unroll
  for (int i=0;i<13;i++){
    int k = i*256+t;
    if (k < F_SZ*E_SZ){
      int f = k>>6, e = k&63;
      tile[f*66+e] = f2b(femb[(size_t)sidx[f]*E_SZ + e] * sfv[f]);
    }
  }
  __syncthreads();
  u16* orow = embT + (size_t)b*KP;
  #pragma unroll
  for (int i=0;i<16;i++){
    int k = i*256+t;           // k = e*64+f
    int f = k&63, e = k>>6;
    orow[k] = (f < F_SZ) ? tile[f*66+e] : (u16)0;
  }
}

// ---------------- product_linear (D,F,E) fp32 -> WlT (D, e*64+f) bf16 zero-padded
__global__ __launch_bounds__(256) void k_wlt(const float* __restrict__ Wl, u16* __restrict__ WlT)
{
  __shared__ u16 tile[F_SZ*66];
  const int d = blockIdx.x, t = threadIdx.x;
  #pragma unroll
  for (int i=0;i<13;i++){
    int k = i*256+t;
    if (k < F_SZ*E_SZ) tile[(k>>6)*66 + (k&63)] = f2b(Wl[(size_t)d*(F_SZ*E_SZ) + k]);
  }
  __syncthreads();
  u16* orow = WlT + (size_t)d*KP;
  #pragma unroll
  for (int i=0;i<16;i++){
    int k = i*256+t;
    int f = k&63, e = k>>6;
    orow[k] = (f < F_SZ) ? tile[f*66+e] : (u16)0;
  }
}

// ---------------- product_quadratic_inner (D,F) fp32 -> PqTp (D,64) bf16 padded
__global__ void k_pqt(const float* __restrict__ Pq, u16* __restrict__ PqTp){
  int idx = blockIdx.x*256 + threadIdx.x;   // grid 128 -> 32768
  int d = idx >> 6, f = idx & 63;
  PqTp[idx] = (f < F_SZ) ? f2b(Pq[d*F_SZ + f]) : (u16)0;
}

// ---------------- (K,N) fp32 -> (N,K) bf16 transpose for dense weights
__global__ void k_transpose(const float* __restrict__ W, u16* __restrict__ WT,
                            int klog2, int N, int total){
  int idx = blockIdx.x*256 + threadIdx.x;
  if (idx < total){
    int k = idx & ((1<<klog2)-1), n = idx >> klog2;
    WT[idx] = f2b(W[(size_t)k*N + n]);
  }
}

// ---------------- cvec[h] += sum_{d in chunk} pbias[d]*W0[d][h] (+ b0[h] once)
__global__ __launch_bounds__(256) void k_cvec(
    const float* __restrict__ pb, const float* __restrict__ W0,
    const float* __restrict__ b0, float* __restrict__ cvec)
{
  int h = blockIdx.x*256 + threadIdx.x;
  int d0 = blockIdx.y*64;
  float acc = (blockIdx.y == 0) ? b0[h] : 0.f;
  #pragma unroll 8
  for (int d=0; d<64; d++) acc += pb[d0+d]*W0[(size_t)(d0+d)*H1_SZ + h];
  atomicAdd(&cvec[h], acc);
}

// XOR-swizzled LDS tile layout (breaks the 16-way bank conflict of plain
// row-major 128B-stride tiles):  LDS slot (row, block j) holds the global
// 8-elem column block (j XOR (row&7)).  Staged with gload16 by fetching
// global block ((lane&7) XOR lr) into lane slot; read back with offset
// ((Q XOR (row&7))*8).  Rows used by fragments satisfy row&7 == l16&7.

// ---------------- fused product layer (r7 structure + swizzle): 512 threads,
// 128b x 128d tile; wave = 32m x 64n. One pass computes lz (GEMM vs WlT) and
// lp (per e-chunk S_e vs register-resident Pq frags, squared, accumulated).
__global__ __launch_bounds__(512) void k_prod(
    const u16* __restrict__ A,     // embT (B, KP)
    const u16* __restrict__ Bm,    // WlT  (D, KP)
    const u16* __restrict__ Pp,    // PqTp (D, 64)
    const float* __restrict__ pbias,
    u16* __restrict__ y0)          // (B, D)
{
  __shared__ __align__(16) u16 As[128*64];
  __shared__ __align__(16) u16 Bs[128*64];
  const int tid  = threadIdx.x;
  const int wave = tid >> 6, lane = tid & 63;
  const int quad = lane >> 4, l16 = lane & 15;
  const int n0 = blockIdx.x * 128, m0 = blockIdx.y * 128;
  const int wr = wave >> 1, wc = wave & 1;   // wr 0..3 (32 m-rows), wc 0..1 (64 n)
  const int lr  = lane >> 3;
  const int lcs = (((lane & 7) ^ lr)) * 8;   // swizzled global column block
  const int sw  = (l16 & 7);                 // fragment-read swizzle key

  // loop-invariant P fragments: rows = d, k = f (global reads, no LDS)
  bf16x8v pfr[4][2];
  #pragma unroll
  for (int nt=0;nt<4;nt++)
    #pragma unroll
    for (int ks=0;ks<2;ks++)
      pfr[nt][ks] = *(const bf16x8v*)&Pp[(n0 + wc*64 + nt*16 + l16)*64 + ks*32 + quad*8];

  f32x4v acc[2][4];   // lz accumulator
  f32x4v lpa[2][4];   // sum over e of S_e^2
  #pragma unroll
  for (int i=0;i<2;i++)
    #pragma unroll
    for (int j=0;j<4;j++){
      acc[i][j] = (f32x4v){0.f,0.f,0.f,0.f};
      lpa[i][j] = (f32x4v){0.f,0.f,0.f,0.f};
    }
  const f32x4v zz = {0.f,0.f,0.f,0.f};

  for (int k0 = 0; k0 < KP; k0 += 64){
    __syncthreads();
    // 8 waves stage As(128 rows) + Bs(128 rows): 2+2 gload16 calls per wave
    #pragma unroll
    for (int c=0;c<2;c++){
      const int r0 = (wave + c*8) * 8;       // 8 rows per 16B-call
      gload16(A  + (size_t)(m0 + r0 + lr)*KP + k0 + lcs, As + r0*64);
      gload16(Bm + (size_t)(n0 + r0 + lr)*KP + k0 + lcs, Bs + r0*64);
    }
    __syncthreads();

    bf16x8v af[2][2];
    #pragma unroll
    for (int ks=0;ks<2;ks++)
      #pragma unroll
      for (int mt=0;mt<2;mt++)
        af[ks][mt] = *(const bf16x8v*)&As[(wr*32+mt*16+l16)*64 + (((ks*4+quad) ^ sw))*8];

    // lz: C += A * WlT^T over this chunk
    #pragma unroll
    for (int ks=0; ks<2; ks++){
      bf16x8v bfr[4];
      #pragma unroll
      for (int nt=0;nt<4;nt++)
        bfr[nt] = *(const bf16x8v*)&Bs[(wc*64+nt*16+l16)*64 + (((ks*4+quad) ^ sw))*8];
      #pragma unroll
      for (int mt=0;mt<2;mt++)
        #pragma unroll
        for (int nt=0;nt<4;nt++)
          acc[mt][nt] = __builtin_amdgcn_mfma_f32_16x16x32_bf16(af[ks][mt], bfr[nt], acc[mt][nt], 0, 0, 0);
    }

    // lp: S_e = A_chunk * Pq^T (K=64), then lpa += S_e .* S_e
    #pragma unroll
    for (int nt=0;nt<4;nt++){
      f32x4v s[2];
      #pragma unroll
      for (int mt=0;mt<2;mt++)
        s[mt] = __builtin_amdgcn_mfma_f32_16x16x32_bf16(af[0][mt], pfr[nt][0], zz, 0, 0, 0);
      #pragma unroll
      for (int mt=0;mt<2;mt++)
        s[mt] = __builtin_amdgcn_mfma_f32_16x16x32_bf16(af[1][mt], pfr[nt][1], s[mt], 0, 0, 0);
      #pragma unroll
      for (int mt=0;mt<2;mt++)
        #pragma unroll
        for (int r=0;r<4;r++)
          lpa[mt][nt][r] = fmaf(s[mt][r], s[mt][r], lpa[mt][nt][r]);
    }
  }

  // epilogue; C/D layout: n = lane&15, m = quad*4 + reg
  #pragma unroll
  for (int nt=0;nt<4;nt++){
    const int n = n0 + wc*64 + nt*16 + l16;
    const float bv = pbias[n];
    #pragma unroll
    for (int mt=0;mt<2;mt++){
      const int mb = m0 + wr*32 + mt*16 + quad*4;
      #pragma unroll
      for (int r=0;r<4;r++){
        float v = acc[mt][nt][r] + sqrtf(lpa[mt][nt][r]) + bv;
        v = (v > 0.f ? v : 0.f) - bv;
        y0[(size_t)(mb+r)*D_SZ + n] = f2b(v);
      }
    }
  }
}

// ---------------- m97-style BT GEMM (+swizzle): C = A * Bm^T, bf16 inputs
// DO_STATS: add fp32 bias[n], atomically accumulate per-column sum/sumsq.
template<int DO_STATS, typename CT>
__global__ __launch_bounds__(256) void gemm_bt(
    const u16* __restrict__ A, const u16* __restrict__ Bm,
    CT* __restrict__ C, const float* __restrict__ bias,
    float* __restrict__ S1, float* __restrict__ S2,
    int M, int N, int K)
{
  __shared__ __align__(16) u16 As[128*64];
  __shared__ __align__(16) u16 Bs[128*64];
  const int tid  = threadIdx.x;
  const int wave = tid >> 6, lane = tid & 63;
  const int quad = lane >> 4, l16 = lane & 15;
  const int n0 = blockIdx.x * 128, m0 = blockIdx.y * 128;
  const int wr = wave >> 1, wc = wave & 1;
  const int lr  = lane >> 3;
  const int lcs = (((lane & 7) ^ lr)) * 8;
  const int sw  = (l16 & 7);

  f32x4v acc[4][4];
  #pragma unroll
  for (int i=0;i<4;i++)
    #pragma unroll
    for (int j=0;j<4;j++)
      acc[i][j] = (f32x4v){0.f,0.f,0.f,0.f};

  for (int k0 = 0; k0 < K; k0 += 64){
    __syncthreads();
    #pragma unroll
    for (int c=0;c<4;c++){
      const int r0 = wave*32 + 8*c;          // 8 rows per 16B-call
      gload16(A  + (size_t)(m0 + r0 + lr)*K + k0 + lcs, As + r0*64);
      gload16(Bm + (size_t)(n0 + r0 + lr)*K + k0 + lcs, Bs + r0*64);
    }
    __syncthreads();
    #pragma unroll
    for (int ks=0; ks<2; ks++){
      bf16x8v af[4], bfr[4];
      #pragma unroll
      for (int mt=0;mt<4;mt++)
        af[mt] = *(const bf16x8v*)&As[(wr*64+mt*16+l16)*64 + (((ks*4+quad) ^ sw))*8];
      #pragma unroll
      for (int nt=0;nt<4;nt++)
        bfr[nt] = *(const bf16x8v*)&Bs[(wc*64+nt*16+l16)*64 + (((ks*4+quad) ^ sw))*8];
      #pragma unroll
      for (int mt=0;mt<4;mt++)
        #pragma unroll
        for (int nt=0;nt<4;nt++)
          acc[mt][nt] = __builtin_amdgcn_mfma_f32_16x16x32_bf16(af[mt], bfr[nt], acc[mt][nt], 0, 0, 0);
    }
  }

  // epilogue; C/D layout: n = lane&15, m = quad*4 + reg
  #pragma unroll
  for (int nt=0;nt<4;nt++){
    const int n = n0 + wc*64 + nt*16 + l16;
    float bv = 0.f;
    if (DO_STATS) bv = bias[n];
    float ls1 = 0.f, ls2 = 0.f;
    #pragma unroll
    for (int mt=0;mt<4;mt++){
      const int mb = m0 + wr*64 + mt*16 + quad*4;
      #pragma unroll
      for (int r=0;r<4;r++){
        float v = acc[mt][nt][r] + bv;
        if constexpr (sizeof(CT) == 2) C[(size_t)(mb+r)*N + n] = f2b(v);
        else                           C[(size_t)(mb+r)*N + n] = v;
        ls1 += v; ls2 += v*v;
      }
    }
    if (DO_STATS){
      ls1 += __shfl_xor(ls1, 16); ls2 += __shfl_xor(ls2, 16);
      ls1 += __shfl_xor(ls1, 32); ls2 += __shfl_xor(ls2, 32);
      if (quad == 0){ atomicAdd(&S1[n], ls1); atomicAdd(&S2[n], ls2); }
    }
  }
}

// ---------------- BN finalize: per-column scale/offset from sums
__global__ void k_bnfin(const float* __restrict__ S1, const float* __restrict__ S2, int n,
                        const float* __restrict__ bnsc, const float* __restrict__ bnof,
                        float* __restrict__ Aout, float* __restrict__ Bout)
{
  int i = blockIdx.x*256 + threadIdx.x;
  if (i < n){
    const float invB = 1.f / 16384.f;
    float m   = S1[i]*invB;
    float var = S2[i]*invB - m*m;
    float a   = bnsc[0] * rsqrtf(var + 1e-10f);
    Aout[i] = a;
    Bout[i] = bnof[0] - m*a;
  }
}

// ---------------- BN apply + relu: fp32 Z in, bf16 Y out, 8 elems/thread
__global__ __launch_bounds__(256) void k_bnapply(
    const float* __restrict__ Z, u16* __restrict__ Y,
    const float* __restrict__ Aa, const float* __restrict__ Bb, int nmask)
{
  size_t base = ((size_t)blockIdx.x*256 + threadIdx.x) * 8;
  int n0 = (int)(base & (size_t)nmask);
  float4 za = *(const float4*)&Z[base];
  float4 zb = *(const float4*)&Z[base+4];
  float zz[8] = {za.x,za.y,za.z,za.w,zb.x,zb.y,zb.z,zb.w};
  union { uint4 q; u16 s[8]; } o;
  #pragma unroll
  for (int j=0;j<8;j++){
    float v = zz[j] * Aa[n0+j] + Bb[n0+j];
    o.s[j] = f2b(v > 0.f ? v : 0.f);
  }
  *(uint4*)&Y[base] = o.q;
}

// ---------------- final dot + sigmoid, one wave per row; fp32 w and out
__global__ __launch_bounds__(256) void k_out(
    const u16* __restrict__ Y2, const float* __restrict__ wvec,
    const float* __restrict__ obp, float* __restrict__ out)
{
  const int wave = threadIdx.x >> 6, lane = threadIdx.x & 63;
  const int b = blockIdx.x*4 + wave;
  union { uint4 q; u16 s[8]; } y;
  y.q = *(const uint4*)&Y2[(size_t)b*H2_SZ + lane*8];
  float4 wa = *(const float4*)&wvec[lane*8];
  float4 wb = *(const float4*)&wvec[lane*8+4];
  float wv[8] = {wa.x,wa.y,wa.z,wa.w,wb.x,wb.y,wb.z,wb.w};
  float s = 0.f;
  #pragma unroll
  for (int j=0;j<8;j++) s += b2f(y.s[j]) * wv[j];
  s += __shfl_xor(s,1);  s += __shfl_xor(s,2);  s += __shfl_xor(s,4);
  s += __shfl_xor(s,8);  s += __shfl_xor(s,16); s += __shfl_xor(s,32);
  if (lane == 0){
    float x = s + obp[0];
    out[b] = 1.f / (1.f + expf(-x));
  }
}

// ---------------- workspace map (bytes) ----------------
// embT @ 0          : 134217728   (dead after k_prod; reused:)
//   z1 @ 0          :  67108864   (fp32 pre-BN layer0)
//   y1 @ 67108864   :  33554432   (bf16 post-BN layer0)
//   z2 @ 100663296  :  33554432   (fp32 pre-BN layer1)
// WlT  @ 134217728  :   4194304   (dead after k_prod)
// y0   @ 138412032  :  16777216   (bf16, bias-centered)
// W0T  @ 155189248  :   1048576
// W1T  @ 156237824  :   1048576
// y2   @ 157286400  :  16777216   (bf16 post-BN layer1)
// stats@ 174063616  : 16 KB ZEROED: S1a[1024] S2a[1024] S1b[512] S2b[512] cvec[1024]
//                     then A0[1024] B0[1024] A1[512] B1[512]
// pqT  @ 174096384  :     65536
// total ~ 174.2 MB

extern "C" void kernel_launch(void* const* d_in, const int* in_sizes, int n_in,
                              void* d_out, int out_size, void* d_ws, size_t ws_size,
                              hipStream_t stream)
{
  const int*   fidx  = (const int*)d_in[0];
  const float* fval  = (const float*)d_in[1];
  const float* femb  = (const float*)d_in[2];
  const float* wl    = (const float*)d_in[3];
  const float* pbias = (const float*)d_in[4];
  const float* pq    = (const float*)d_in[5];
  const float* w0    = (const float*)d_in[6];
  const float* b0    = (const float*)d_in[7];
  const float* w1    = (const float*)d_in[8];
  const float* b1    = (const float*)d_in[9];
  const float* bnsc  = (const float*)d_in[10];
  const float* bnof  = (const float*)d_in[11];
  const float* ow    = (const float*)d_in[12];
  const float* ob    = (const float*)d_in[13];
  float* out = (float*)d_out;

  char* ws = (char*)d_ws;
  u16*   embT = (u16*)(ws + 0);
  float* z1b  = (float*)(ws + 0);
  u16*   y1b  = (u16*)(ws + 67108864);
  float* z2b  = (float*)(ws + 100663296);
  u16*   wlT  = (u16*)(ws + 134217728);
  u16*   y0b  = (u16*)(ws + 138412032);
  u16*   w0T  = (u16*)(ws + 155189248);
  u16*   w1T  = (u16*)(ws + 156237824);
  u16*   y2b  = (u16*)(ws + 157286400);
  float* S1a  = (float*)(ws + 174063616);
  float* S2a  = S1a + 1024;
  float* S1b  = S2a + 1024;
  float* S2b  = S1b + 512;
  float* cvec = S2b + 512;
  float* A0   = cvec + 1024;
  float* B0   = A0 + 1024;
  float* A1   = B0 + 1024;
  float* B1   = A1 + 512;
  u16*   pqT  = (u16*)(ws + 174096384);

  hipMemsetAsync((void*)S1a, 0, 16384, stream);      // S1a,S2a,S1b,S2b,cvec

  k_gather<<<B_SZ, 256, 0, stream>>>(fidx, fval, femb, embT);
  k_wlt<<<D_SZ, 256, 0, stream>>>(wl, wlT);
  k_pqt<<<128, 256, 0, stream>>>(pq, pqT);
  k_transpose<<<2048, 256, 0, stream>>>(w0, w0T, 9, 1024, 524288);   // (512,1024)->(1024,512)
  k_transpose<<<2048, 256, 0, stream>>>(w1, w1T, 10, 512, 524288);   // (1024,512)->(512,1024)
  k_cvec<<<dim3(4,8), 256, 0, stream>>>(pbias, w0, b0, cvec);

  k_prod<<<dim3(4,128), 512, 0, stream>>>(embT, wlT, pqT, pbias, y0b);

  gemm_bt<1,float><<<dim3(8,128), 256, 0, stream>>>(y0b, w0T, z1b, cvec, S1a, S2a,
                                                    B_SZ, H1_SZ, D_SZ);
  k_bnfin<<<4, 256, 0, stream>>>(S1a, S2a, 1024, bnsc, bnof, A0, B0);
  k_bnapply<<<8192, 256, 0, stream>>>(z1b, y1b, A0, B0, 1023);

  gemm_bt<1,float><<<dim3(4,128), 256, 0, stream>>>(y1b, w1T, z2b, b1, S1b, S2b,
                                                    B_SZ, H2_SZ, H1_SZ);
  k_bnfin<<<2, 256, 0, stream>>>(S1b, S2b, 512, bnsc, bnof, A1, B1);
  k_bnapply<<<4096, 256, 0, stream>>>(z2b, y2b, A1, B1, 511);

  k_out<<<4096, 256, 0, stream>>>(y2b, ow, ob, out);
}

// Round 10
// 418.603 us; speedup vs baseline: 1.5075x; 1.0589x over previous
//
#include <hip/hip_runtime.h>

typedef unsigned short u16;
typedef __attribute__((ext_vector_type(8))) short bf16x8v;
typedef __attribute__((ext_vector_type(4))) float f32x4v;

#define B_SZ 16384
#define F_SZ 50
#define E_SZ 64
#define D_SZ 512
#define H1_SZ 1024
#define H2_SZ 512
#define KP 4096   // padded product-layer K: (e*64+f), f padded 50->64

__device__ __forceinline__ float b2f(u16 u){
  union { unsigned int i; float f; } v; v.i = ((unsigned int)u) << 16; return v.f;
}
__device__ __forceinline__ u16 f2b(float f){
  union { float f; unsigned int i; } v; v.f = f;
  unsigned int r = v.i + 0x7FFFu + ((v.i >> 16) & 1u);
  return (u16)(r >> 16);
}

// async global->LDS, 16B/lane. g is per-lane (base + lane*16B); lds base is
// wave-uniform; HW writes lds_base + lane*16.
__device__ __forceinline__ void gload16(const u16* g, u16* lds_base_uniform){
#if __has_builtin(__builtin_amdgcn_global_load_lds)
  __builtin_amdgcn_global_load_lds(
      (const __attribute__((address_space(1))) unsigned int*)g,
      (__attribute__((address_space(3))) unsigned int*)lds_base_uniform,
      16, 0, 0);
#else
  int lane = threadIdx.x & 63;
  *(uint4*)(lds_base_uniform + lane*8) = *(const uint4*)g;
#endif
}

// ---------------- gather: embT[b][e*64+f] = fe[idx[b,f],e]*fv[b,f] (bf16), f>=50 -> 0
__global__ __launch_bounds__(256) void k_gather(
    const int* __restrict__ fidx, const float* __restrict__ fval,
    const float* __restrict__ femb, u16* __restrict__ embT)
{
  __shared__ int   sidx[F_SZ];
  __shared__ float sfv[F_SZ];
  __shared__ u16   tile[F_SZ*66];   // padded stride 66 to break bank conflicts
  const int b = blockIdx.x, t = threadIdx.x;
  if (t < F_SZ){ sidx[t] = fidx[b*F_SZ+t]; sfv[t] = fval[b*F_SZ+t]; }
  __syncthreads();
  #pragma unroll
  for (int i=0;i<13;i++){
    int k = i*256+t;
    if (k < F_SZ*E_SZ){
      int f = k>>6, e = k&63;
      tile[f*66+e] = f2b(femb[(size_t)sidx[f]*E_SZ + e] * sfv[f]);
    }
  }
  __syncthreads();
  u16* orow = embT + (size_t)b*KP;
  #pragma unroll
  for (int i=0;i<16;i++){
    int k = i*256+t;           // k = e*64+f
    int f = k&63, e = k>>6;
    orow[k] = (f < F_SZ) ? tile[f*66+e] : (u16)0;
  }
}

// ---------------- product_linear (D,F,E) fp32 -> WlT (D, e*64+f) bf16 zero-padded
__global__ __launch_bounds__(256) void k_wlt(const float* __restrict__ Wl, u16* __restrict__ WlT)
{
  __shared__ u16 tile[F_SZ*66];
  const int d = blockIdx.x, t = threadIdx.x;
  #pragma unroll
  for (int i=0;i<13;i++){
    int k = i*256+t;
    if (k < F_SZ*E_SZ) tile[(k>>6)*66 + (k&63)] = f2b(Wl[(size_t)d*(F_SZ*E_SZ) + k]);
  }
  __syncthreads();
  u16* orow = WlT + (size_t)d*KP;
  #pragma unroll
  for (int i=0;i<16;i++){
    int k = i*256+t;
    int f = k&63, e = k>>6;
    orow[k] = (f < F_SZ) ? tile[f*66+e] : (u16)0;
  }
}

// ---------------- product_quadratic_inner (D,F) fp32 -> PqTp (D,64) bf16 padded
__global__ void k_pqt(const float* __restrict__ Pq, u16* __restrict__ PqTp){
  int idx = blockIdx.x*256 + threadIdx.x;   // grid 128 -> 32768
  int d = idx >> 6, f = idx & 63;
  PqTp[idx] = (f < F_SZ) ? f2b(Pq[d*F_SZ + f]) : (u16)0;
}

// ---------------- (K,N) fp32 -> (N,K) bf16 transpose for dense weights
__global__ void k_transpose(const float* __restrict__ W, u16* __restrict__ WT,
                            int klog2, int N, int total){
  int idx = blockIdx.x*256 + threadIdx.x;
  if (idx < total){
    int k = idx & ((1<<klog2)-1), n = idx >> klog2;
    WT[idx] = f2b(W[(size_t)k*N + n]);
  }
}

// ---------------- cvec[h] += sum_{d in chunk} pbias[d]*W0[d][h] (+ b0[h] once)
__global__ __launch_bounds__(256) void k_cvec(
    const float* __restrict__ pb, const float* __restrict__ W0,
    const float* __restrict__ b0, float* __restrict__ cvec)
{
  int h = blockIdx.x*256 + threadIdx.x;
  int d0 = blockIdx.y*64;
  float acc = (blockIdx.y == 0) ? b0[h] : 0.f;
  #pragma unroll 8
  for (int d=0; d<64; d++) acc += pb[d0+d]*W0[(size_t)(d0+d)*H1_SZ + h];
  atomicAdd(&cvec[h], acc);
}

// XOR-swizzled LDS tile layout (r9: kills the 16-way bank conflict, verified
// SQ_LDS_BANK_CONFLICT -> 0):  LDS slot (row, block j) holds global 8-elem
// column block (j XOR (row&7)); staged by fetching global block
// ((lane&7) XOR lr); fragments read offset ((Q XOR (l16&7))*8).

// ---------------- fused product layer v5: 256 threads, 64b x 128d tile
// (3 blocks/CU co-resident -> inter-block overlap of the barrier drain).
// Wave = 32m x 64n. One pass computes lz (GEMM vs WlT) and lp (per e-chunk
// S_e vs register-resident Pq frags, squared, accumulated).
// Epilogue: y0 = relu(lz + sqrt(lp) + pbias) - pbias   (bias-centered bf16).
__global__ __launch_bounds__(256) void k_prod(
    const u16* __restrict__ A,     // embT (B, KP)
    const u16* __restrict__ Bm,    // WlT  (D, KP)
    const u16* __restrict__ Pp,    // PqTp (D, 64)
    const float* __restrict__ pbias,
    u16* __restrict__ y0)          // (B, D)
{
  __shared__ __align__(16) u16 As[64*64];     // 8 KB
  __shared__ __align__(16) u16 Bs[128*64];    // 16 KB
  const int tid  = threadIdx.x;
  const int wave = tid >> 6, lane = tid & 63;
  const int quad = lane >> 4, l16 = lane & 15;
  const int n0 = blockIdx.x * 128, m0 = blockIdx.y * 64;
  const int wr = wave >> 1, wc = wave & 1;   // wr 0..1 (32 m-rows), wc 0..1 (64 n)
  const int lr  = lane >> 3;
  const int lcs = (((lane & 7) ^ lr)) * 8;   // swizzled global column block
  const int sw  = (l16 & 7);                 // fragment-read swizzle key

  // loop-invariant P fragments: rows = d, k = f (global reads, no LDS)
  bf16x8v pfr[4][2];
  #pragma unroll
  for (int nt=0;nt<4;nt++)
    #pragma unroll
    for (int ks=0;ks<2;ks++)
      pfr[nt][ks] = *(const bf16x8v*)&Pp[(n0 + wc*64 + nt*16 + l16)*64 + ks*32 + quad*8];

  f32x4v acc[2][4];   // lz accumulator
  f32x4v lpa[2][4];   // sum over e of S_e^2
  #pragma unroll
  for (int i=0;i<2;i++)
    #pragma unroll
    for (int j=0;j<4;j++){
      acc[i][j] = (f32x4v){0.f,0.f,0.f,0.f};
      lpa[i][j] = (f32x4v){0.f,0.f,0.f,0.f};
    }
  const f32x4v zz = {0.f,0.f,0.f,0.f};

  for (int k0 = 0; k0 < KP; k0 += 64){
    __syncthreads();
    // 4 waves stage As(64 rows, 2 calls/wave) + Bs(128 rows, 4 calls/wave)
    #pragma unroll
    for (int c=0;c<2;c++){
      const int r0 = wave*16 + c*8;
      gload16(A + (size_t)(m0 + r0 + lr)*KP + k0 + lcs, As + r0*64);
    }
    #pragma unroll
    for (int c=0;c<4;c++){
      const int r0 = wave*32 + c*8;
      gload16(Bm + (size_t)(n0 + r0 + lr)*KP + k0 + lcs, Bs + r0*64);
    }
    __syncthreads();

    bf16x8v af[2][2];
    #pragma unroll
    for (int ks=0;ks<2;ks++)
      #pragma unroll
      for (int mt=0;mt<2;mt++)
        af[ks][mt] = *(const bf16x8v*)&As[(wr*32+mt*16+l16)*64 + (((ks*4+quad) ^ sw))*8];

    // lz: C += A * WlT^T over this chunk
    #pragma unroll
    for (int ks=0; ks<2; ks++){
      bf16x8v bfr[4];
      #pragma unroll
      for (int nt=0;nt<4;nt++)
        bfr[nt] = *(const bf16x8v*)&Bs[(wc*64+nt*16+l16)*64 + (((ks*4+quad) ^ sw))*8];
      #pragma unroll
      for (int mt=0;mt<2;mt++)
        #pragma unroll
        for (int nt=0;nt<4;nt++)
          acc[mt][nt] = __builtin_amdgcn_mfma_f32_16x16x32_bf16(af[ks][mt], bfr[nt], acc[mt][nt], 0, 0, 0);
    }

    // lp: S_e = A_chunk * Pq^T (K=64), then lpa += S_e .* S_e
    #pragma unroll
    for (int nt=0;nt<4;nt++){
      f32x4v s[2];
      #pragma unroll
      for (int mt=0;mt<2;mt++)
        s[mt] = __builtin_amdgcn_mfma_f32_16x16x32_bf16(af[0][mt], pfr[nt][0], zz, 0, 0, 0);
      #pragma unroll
      for (int mt=0;mt<2;mt++)
        s[mt] = __builtin_amdgcn_mfma_f32_16x16x32_bf16(af[1][mt], pfr[nt][1], s[mt], 0, 0, 0);
      #pragma unroll
      for (int mt=0;mt<2;mt++)
        #pragma unroll
        for (int r=0;r<4;r++)
          lpa[mt][nt][r] = fmaf(s[mt][r], s[mt][r], lpa[mt][nt][r]);
    }
  }

  // epilogue; C/D layout: n = lane&15, m = quad*4 + reg
  #pragma unroll
  for (int nt=0;nt<4;nt++){
    const int n = n0 + wc*64 + nt*16 + l16;
    const float bv = pbias[n];
    #pragma unroll
    for (int mt=0;mt<2;mt++){
      const int mb = m0 + wr*32 + mt*16 + quad*4;
      #pragma unroll
      for (int r=0;r<4;r++){
        float v = acc[mt][nt][r] + sqrtf(lpa[mt][nt][r]) + bv;
        v = (v > 0.f ? v : 0.f) - bv;
        y0[(size_t)(mb+r)*D_SZ + n] = f2b(v);
      }
    }
  }
}

// ---------------- m97-style BT GEMM (+swizzle): C = A * Bm^T, bf16 inputs
// DO_STATS: add fp32 bias[n], atomically accumulate per-column sum/sumsq.
template<int DO_STATS, typename CT>
__global__ __launch_bounds__(256) void gemm_bt(
    const u16* __restrict__ A, const u16* __restrict__ Bm,
    CT* __restrict__ C, const float* __restrict__ bias,
    float* __restrict__ S1, float* __restrict__ S2,
    int M, int N, int K)
{
  __shared__ __align__(16) u16 As[128*64];
  __shared__ __align__(16) u16 Bs[128*64];
  const int tid  = threadIdx.x;
  const int wave = tid >> 6, lane = tid & 63;
  const int quad = lane >> 4, l16 = lane & 15;
  const int n0 = blockIdx.x * 128, m0 = blockIdx.y * 128;
  const int wr = wave >> 1, wc = wave & 1;
  const int lr  = lane >> 3;
  const int lcs = (((lane & 7) ^ lr)) * 8;
  const int sw  = (l16 & 7);

  f32x4v acc[4][4];
  #pragma unroll
  for (int i=0;i<4;i++)
    #pragma unroll
    for (int j=0;j<4;j++)
      acc[i][j] = (f32x4v){0.f,0.f,0.f,0.f};

  for (int k0 = 0; k0 < K; k0 += 64){
    __syncthreads();
    #pragma unroll
    for (int c=0;c<4;c++){
      const int r0 = wave*32 + 8*c;          // 8 rows per 16B-call
      gload16(A  + (size_t)(m0 + r0 + lr)*K + k0 + lcs, As + r0*64);
      gload16(Bm + (size_t)(n0 + r0 + lr)*K + k0 + lcs, Bs + r0*64);
    }
    __syncthreads();
    #pragma unroll
    for (int ks=0; ks<2; ks++){
      bf16x8v af[4], bfr[4];
      #pragma unroll
      for (int mt=0;mt<4;mt++)
        af[mt] = *(const bf16x8v*)&As[(wr*64+mt*16+l16)*64 + (((ks*4+quad) ^ sw))*8];
      #pragma unroll
      for (int nt=0;nt<4;nt++)
        bfr[nt] = *(const bf16x8v*)&Bs[(wc*64+nt*16+l16)*64 + (((ks*4+quad) ^ sw))*8];
      #pragma unroll
      for (int mt=0;mt<4;mt++)
        #pragma unroll
        for (int nt=0;nt<4;nt++)
          acc[mt][nt] = __builtin_amdgcn_mfma_f32_16x16x32_bf16(af[mt], bfr[nt], acc[mt][nt], 0, 0, 0);
    }
  }

  // epilogue; C/D layout: n = lane&15, m = quad*4 + reg
  #pragma unroll
  for (int nt=0;nt<4;nt++){
    const int n = n0 + wc*64 + nt*16 + l16;
    float bv = 0.f;
    if (DO_STATS) bv = bias[n];
    float ls1 = 0.f, ls2 = 0.f;
    #pragma unroll
    for (int mt=0;mt<4;mt++){
      const int mb = m0 + wr*64 + mt*16 + quad*4;
      #pragma unroll
      for (int r=0;r<4;r++){
        float v = acc[mt][nt][r] + bv;
        if constexpr (sizeof(CT) == 2) C[(size_t)(mb+r)*N + n] = f2b(v);
        else                           C[(size_t)(mb+r)*N + n] = v;
        ls1 += v; ls2 += v*v;
      }
    }
    if (DO_STATS){
      ls1 += __shfl_xor(ls1, 16); ls2 += __shfl_xor(ls2, 16);
      ls1 += __shfl_xor(ls1, 32); ls2 += __shfl_xor(ls2, 32);
      if (quad == 0){ atomicAdd(&S1[n], ls1); atomicAdd(&S2[n], ls2); }
    }
  }
}

// ---------------- BN finalize: per-column scale/offset from sums
__global__ void k_bnfin(const float* __restrict__ S1, const float* __restrict__ S2, int n,
                        const float* __restrict__ bnsc, const float* __restrict__ bnof,
                        float* __restrict__ Aout, float* __restrict__ Bout)
{
  int i = blockIdx.x*256 + threadIdx.x;
  if (i < n){
    const float invB = 1.f / 16384.f;
    float m   = S1[i]*invB;
    float var = S2[i]*invB - m*m;
    float a   = bnsc[0] * rsqrtf(var + 1e-10f);
    Aout[i] = a;
    Bout[i] = bnof[0] - m*a;
  }
}

// ---------------- BN apply + relu: fp32 Z in, bf16 Y out, 8 elems/thread
__global__ __launch_bounds__(256) void k_bnapply(
    const float* __restrict__ Z, u16* __restrict__ Y,
    const float* __restrict__ Aa, const float* __restrict__ Bb, int nmask)
{
  size_t base = ((size_t)blockIdx.x*256 + threadIdx.x) * 8;
  int n0 = (int)(base & (size_t)nmask);
  float4 za = *(const float4*)&Z[base];
  float4 zb = *(const float4*)&Z[base+4];
  float zz[8] = {za.x,za.y,za.z,za.w,zb.x,zb.y,zb.z,zb.w};
  union { uint4 q; u16 s[8]; } o;
  #pragma unroll
  for (int j=0;j<8;j++){
    float v = zz[j] * Aa[n0+j] + Bb[n0+j];
    o.s[j] = f2b(v > 0.f ? v : 0.f);
  }
  *(uint4*)&Y[base] = o.q;
}

// ---------------- final dot + sigmoid, one wave per row; fp32 w and out
__global__ __launch_bounds__(256) void k_out(
    const u16* __restrict__ Y2, const float* __restrict__ wvec,
    const float* __restrict__ obp, float* __restrict__ out)
{
  const int wave = threadIdx.x >> 6, lane = threadIdx.x & 63;
  const int b = blockIdx.x*4 + wave;
  union { uint4 q; u16 s[8]; } y;
  y.q = *(const uint4*)&Y2[(size_t)b*H2_SZ + lane*8];
  float4 wa = *(const float4*)&wvec[lane*8];
  float4 wb = *(const float4*)&wvec[lane*8+4];
  float wv[8] = {wa.x,wa.y,wa.z,wa.w,wb.x,wb.y,wb.z,wb.w};
  float s = 0.f;
  #pragma unroll
  for (int j=0;j<8;j++) s += b2f(y.s[j]) * wv[j];
  s += __shfl_xor(s,1);  s += __shfl_xor(s,2);  s += __shfl_xor(s,4);
  s += __shfl_xor(s,8);  s += __shfl_xor(s,16); s += __shfl_xor(s,32);
  if (lane == 0){
    float x = s + obp[0];
    out[b] = 1.f / (1.f + expf(-x));
  }
}

// ---------------- workspace map (bytes) ----------------
// embT @ 0          : 134217728   (dead after k_prod; reused:)
//   z1 @ 0          :  67108864   (fp32 pre-BN layer0)
//   y1 @ 67108864   :  33554432   (bf16 post-BN layer0)
//   z2 @ 100663296  :  33554432   (fp32 pre-BN layer1)
// WlT  @ 134217728  :   4194304   (dead after k_prod)
// y0   @ 138412032  :  16777216   (bf16, bias-centered)
// W0T  @ 155189248  :   1048576
// W1T  @ 156237824  :   1048576
// y2   @ 157286400  :  16777216   (bf16 post-BN layer1)
// stats@ 174063616  : 16 KB ZEROED: S1a[1024] S2a[1024] S1b[512] S2b[512] cvec[1024]
//                     then A0[1024] B0[1024] A1[512] B1[512]
// pqT  @ 174096384  :     65536
// total ~ 174.2 MB

extern "C" void kernel_launch(void* const* d_in, const int* in_sizes, int n_in,
                              void* d_out, int out_size, void* d_ws, size_t ws_size,
                              hipStream_t stream)
{
  const int*   fidx  = (const int*)d_in[0];
  const float* fval  = (const float*)d_in[1];
  const float* femb  = (const float*)d_in[2];
  const float* wl    = (const float*)d_in[3];
  const float* pbias = (const float*)d_in[4];
  const float* pq    = (const float*)d_in[5];
  const float* w0    = (const float*)d_in[6];
  const float* b0    = (const float*)d_in[7];
  const float* w1    = (const float*)d_in[8];
  const float* b1    = (const float*)d_in[9];
  const float* bnsc  = (const float*)d_in[10];
  const float* bnof  = (const float*)d_in[11];
  const float* ow    = (const float*)d_in[12];
  const float* ob    = (const float*)d_in[13];
  float* out = (float*)d_out;

  char* ws = (char*)d_ws;
  u16*   embT = (u16*)(ws + 0);
  float* z1b  = (float*)(ws + 0);
  u16*   y1b  = (u16*)(ws + 67108864);
  float* z2b  = (float*)(ws + 100663296);
  u16*   wlT  = (u16*)(ws + 134217728);
  u16*   y0b  = (u16*)(ws + 138412032);
  u16*   w0T  = (u16*)(ws + 155189248);
  u16*   w1T  = (u16*)(ws + 156237824);
  u16*   y2b  = (u16*)(ws + 157286400);
  float* S1a  = (float*)(ws + 174063616);
  float* S2a  = S1a + 1024;
  float* S1b  = S2a + 1024;
  float* S2b  = S1b + 512;
  float* cvec = S2b + 512;
  float* A0   = cvec + 1024;
  float* B0   = A0 + 1024;
  float* A1   = B0 + 1024;
  float* B1   = A1 + 512;
  u16*   pqT  = (u16*)(ws + 174096384);

  hipMemsetAsync((void*)S1a, 0, 16384, stream);      // S1a,S2a,S1b,S2b,cvec

  k_gather<<<B_SZ, 256, 0, stream>>>(fidx, fval, femb, embT);
  k_wlt<<<D_SZ, 256, 0, stream>>>(wl, wlT);
  k_pqt<<<128, 256, 0, stream>>>(pq, pqT);
  k_transpose<<<2048, 256, 0, stream>>>(w0, w0T, 9, 1024, 524288);   // (512,1024)->(1024,512)
  k_transpose<<<2048, 256, 0, stream>>>(w1, w1T, 10, 512, 524288);   // (1024,512)->(512,1024)
  k_cvec<<<dim3(4,8), 256, 0, stream>>>(pbias, w0, b0, cvec);

  k_prod<<<dim3(4,256), 256, 0, stream>>>(embT, wlT, pqT, pbias, y0b);

  gemm_bt<1,float><<<dim3(8,128), 256, 0, stream>>>(y0b, w0T, z1b, cvec, S1a, S2a,
                                                    B_SZ, H1_SZ, D_SZ);
  k_bnfin<<<4, 256, 0, stream>>>(S1a, S2a, 1024, bnsc, bnof, A0, B0);
  k_bnapply<<<8192, 256, 0, stream>>>(z1b, y1b, A0, B0, 1023);

  gemm_bt<1,float><<<dim3(4,128), 256, 0, stream>>>(y1b, w1T, z2b, b1, S1b, S2b,
                                                    B_SZ, H2_SZ, H1_SZ);
  k_bnfin<<<2, 256, 0, stream>>>(S1b, S2b, 512, bnsc, bnof, A1, B1);
  k_bnapply<<<4096, 256, 0, stream>>>(z2b, y2b, A1, B1, 511);

  k_out<<<4096, 256, 0, stream>>>(y2b, ow, ob, out);
}

// Round 11
// 406.661 us; speedup vs baseline: 1.5517x; 1.0294x over previous
//
#include <hip/hip_runtime.h>

typedef unsigned short u16;
typedef __attribute__((ext_vector_type(8))) short bf16x8v;
typedef __attribute__((ext_vector_type(4))) float f32x4v;

#define B_SZ 16384
#define F_SZ 50
#define E_SZ 64
#define D_SZ 512
#define H1_SZ 1024
#define H2_SZ 512
#define KP 4096   // padded product-layer K: (e*64+f), f padded 50->64

__device__ __forceinline__ float b2f(u16 u){
  union { unsigned int i; float f; } v; v.i = ((unsigned int)u) << 16; return v.f;
}
__device__ __forceinline__ u16 f2b(float f){
  union { float f; unsigned int i; } v; v.f = f;
  unsigned int r = v.i + 0x7FFFu + ((v.i >> 16) & 1u);
  return (u16)(r >> 16);
}

// async global->LDS, 16B/lane. g is per-lane (base + lane*16B); lds base is
// wave-uniform; HW writes lds_base + lane*16.
__device__ __forceinline__ void gload16(const u16* g, u16* lds_base_uniform){
#if __has_builtin(__builtin_amdgcn_global_load_lds)
  __builtin_amdgcn_global_load_lds(
      (const __attribute__((address_space(1))) unsigned int*)g,
      (__attribute__((address_space(3))) unsigned int*)lds_base_uniform,
      16, 0, 0);
#else
  int lane = threadIdx.x & 63;
  *(uint4*)(lds_base_uniform + lane*8) = *(const uint4*)g;
#endif
}

// XCD-aware grid swizzle: blocks sharing an A(m)-tile get IDs = same (mod 8)
// so they land on the same XCD's L2 (dispatch round-robins id%8 across XCDs).
// x = n-tile (NB=2^nblog2 of them), y = m-tile (multiple of 8 m-tiles).
__device__ __forceinline__ void swz(int id, int nblog2, int &x, int &y){
  int xcd = id & 7, j = id >> 3;
  x = j & ((1 << nblog2) - 1);
  y = ((j >> nblog2) << 3) | xcd;
}

// ---------------- gather: embT[b][e*64+f] = fe[idx[b,f],e]*fv[b,f] (bf16), f>=50 -> 0
__global__ __launch_bounds__(256) void k_gather(
    const int* __restrict__ fidx, const float* __restrict__ fval,
    const float* __restrict__ femb, u16* __restrict__ embT)
{
  __shared__ int   sidx[F_SZ];
  __shared__ float sfv[F_SZ];
  __shared__ u16   tile[F_SZ*66];   // padded stride 66 to break bank conflicts
  const int b = blockIdx.x, t = threadIdx.x;
  if (t < F_SZ){ sidx[t] = fidx[b*F_SZ+t]; sfv[t] = fval[b*F_SZ+t]; }
  __syncthreads();
  #pragma unroll
  for (int i=0;i<13;i++){
    int k = i*256+t;
    if (k < F_SZ*E_SZ){
      int f = k>>6, e = k&63;
      tile[f*66+e] = f2b(femb[(size_t)sidx[f]*E_SZ + e] * sfv[f]);
    }
  }
  __syncthreads();
  u16* orow = embT + (size_t)b*KP;
  #pragma unroll
  for (int i=0;i<16;i++){
    int k = i*256+t;           // k = e*64+f
    int f = k&63, e = k>>6;
    orow[k] = (f < F_SZ) ? tile[f*66+e] : (u16)0;
  }
}

// ---------------- product_linear (D,F,E) fp32 -> WlT (D, e*64+f) bf16 zero-padded
__global__ __launch_bounds__(256) void k_wlt(const float* __restrict__ Wl, u16* __restrict__ WlT)
{
  __shared__ u16 tile[F_SZ*66];
  const int d = blockIdx.x, t = threadIdx.x;
  #pragma unroll
  for (int i=0;i<13;i++){
    int k = i*256+t;
    if (k < F_SZ*E_SZ) tile[(k>>6)*66 + (k&63)] = f2b(Wl[(size_t)d*(F_SZ*E_SZ) + k]);
  }
  __syncthreads();
  u16* orow = WlT + (size_t)d*KP;
  #pragma unroll
  for (int i=0;i<16;i++){
    int k = i*256+t;
    int f = k&63, e = k>>6;
    orow[k] = (f < F_SZ) ? tile[f*66+e] : (u16)0;
  }
}

// ---------------- product_quadratic_inner (D,F) fp32 -> PqTp (D,64) bf16 padded
__global__ void k_pqt(const float* __restrict__ Pq, u16* __restrict__ PqTp){
  int idx = blockIdx.x*256 + threadIdx.x;   // grid 128 -> 32768
  int d = idx >> 6, f = idx & 63;
  PqTp[idx] = (f < F_SZ) ? f2b(Pq[d*F_SZ + f]) : (u16)0;
}

// ---------------- (K,N) fp32 -> (N,K) bf16 transpose for dense weights
__global__ void k_transpose(const float* __restrict__ W, u16* __restrict__ WT,
                            int klog2, int N, int total){
  int idx = blockIdx.x*256 + threadIdx.x;
  if (idx < total){
    int k = idx & ((1<<klog2)-1), n = idx >> klog2;
    WT[idx] = f2b(W[(size_t)k*N + n]);
  }
}

// ---------------- cvec[h] += sum_{d in chunk} pbias[d]*W0[d][h] (+ b0[h] once)
__global__ __launch_bounds__(256) void k_cvec(
    const float* __restrict__ pb, const float* __restrict__ W0,
    const float* __restrict__ b0, float* __restrict__ cvec)
{
  int h = blockIdx.x*256 + threadIdx.x;
  int d0 = blockIdx.y*64;
  float acc = (blockIdx.y == 0) ? b0[h] : 0.f;
  #pragma unroll 8
  for (int d=0; d<64; d++) acc += pb[d0+d]*W0[(size_t)(d0+d)*H1_SZ + h];
  atomicAdd(&cvec[h], acc);
}

// XOR-swizzled LDS tile layout (r9: SQ_LDS_BANK_CONFLICT -> 0): LDS slot
// (row, block j) holds global 8-elem column block (j XOR (row&7)); staged by
// fetching global block ((lane&7) XOR lr); fragments read ((Q XOR (l16&7))*8).

// ---------------- fused product layer v6: 256 threads, 64b x 128d tile,
// XCD-swizzled grid (all 4 n-blocks of an m-tile on one XCD -> embT fetched
// once per XCD). Wave = 32m x 64n. One pass computes lz (GEMM vs WlT) and lp
// (per e-chunk S_e vs register-resident Pq frags, squared, accumulated).
// Epilogue: y0 = relu(lz + sqrt(lp) + pbias) - pbias   (bias-centered bf16).
__global__ __launch_bounds__(256) void k_prod(
    const u16* __restrict__ A,     // embT (B, KP)
    const u16* __restrict__ Bm,    // WlT  (D, KP)
    const u16* __restrict__ Pp,    // PqTp (D, 64)
    const float* __restrict__ pbias,
    u16* __restrict__ y0)          // (B, D)
{
  __shared__ __align__(16) u16 As[64*64];     // 8 KB
  __shared__ __align__(16) u16 Bs[128*64];    // 16 KB
  const int tid  = threadIdx.x;
  const int wave = tid >> 6, lane = tid & 63;
  const int quad = lane >> 4, l16 = lane & 15;
  int bx, by;  swz(blockIdx.x, 2, bx, by);    // NB=4 n-tiles, 256 m-tiles
  const int n0 = bx * 128, m0 = by * 64;
  const int wr = wave >> 1, wc = wave & 1;    // wr 0..1 (32 m-rows), wc 0..1 (64 n)
  const int lr  = lane >> 3;
  const int lcs = (((lane & 7) ^ lr)) * 8;    // swizzled global column block
  const int sw  = (l16 & 7);                  // fragment-read swizzle key

  // loop-invariant P fragments: rows = d, k = f (global reads, no LDS)
  bf16x8v pfr[4][2];
  #pragma unroll
  for (int nt=0;nt<4;nt++)
    #pragma unroll
    for (int ks=0;ks<2;ks++)
      pfr[nt][ks] = *(const bf16x8v*)&Pp[(n0 + wc*64 + nt*16 + l16)*64 + ks*32 + quad*8];

  f32x4v acc[2][4];   // lz accumulator
  f32x4v lpa[2][4];   // sum over e of S_e^2
  #pragma unroll
  for (int i=0;i<2;i++)
    #pragma unroll
    for (int j=0;j<4;j++){
      acc[i][j] = (f32x4v){0.f,0.f,0.f,0.f};
      lpa[i][j] = (f32x4v){0.f,0.f,0.f,0.f};
    }
  const f32x4v zz = {0.f,0.f,0.f,0.f};

  for (int k0 = 0; k0 < KP; k0 += 64){
    __syncthreads();
    // 4 waves stage As(64 rows, 2 calls/wave) + Bs(128 rows, 4 calls/wave)
    #pragma unroll
    for (int c=0;c<2;c++){
      const int r0 = wave*16 + c*8;
      gload16(A + (size_t)(m0 + r0 + lr)*KP + k0 + lcs, As + r0*64);
    }
    #pragma unroll
    for (int c=0;c<4;c++){
      const int r0 = wave*32 + c*8;
      gload16(Bm + (size_t)(n0 + r0 + lr)*KP + k0 + lcs, Bs + r0*64);
    }
    __syncthreads();

    bf16x8v af[2][2];
    #pragma unroll
    for (int ks=0;ks<2;ks++)
      #pragma unroll
      for (int mt=0;mt<2;mt++)
        af[ks][mt] = *(const bf16x8v*)&As[(wr*32+mt*16+l16)*64 + (((ks*4+quad) ^ sw))*8];

    // lz: C += A * WlT^T over this chunk
    #pragma unroll
    for (int ks=0; ks<2; ks++){
      bf16x8v bfr[4];
      #pragma unroll
      for (int nt=0;nt<4;nt++)
        bfr[nt] = *(const bf16x8v*)&Bs[(wc*64+nt*16+l16)*64 + (((ks*4+quad) ^ sw))*8];
      #pragma unroll
      for (int mt=0;mt<2;mt++)
        #pragma unroll
        for (int nt=0;nt<4;nt++)
          acc[mt][nt] = __builtin_amdgcn_mfma_f32_16x16x32_bf16(af[ks][mt], bfr[nt], acc[mt][nt], 0, 0, 0);
    }

    // lp: S_e = A_chunk * Pq^T (K=64), then lpa += S_e .* S_e
    #pragma unroll
    for (int nt=0;nt<4;nt++){
      f32x4v s[2];
      #pragma unroll
      for (int mt=0;mt<2;mt++)
        s[mt] = __builtin_amdgcn_mfma_f32_16x16x32_bf16(af[0][mt], pfr[nt][0], zz, 0, 0, 0);
      #pragma unroll
      for (int mt=0;mt<2;mt++)
        s[mt] = __builtin_amdgcn_mfma_f32_16x16x32_bf16(af[1][mt], pfr[nt][1], s[mt], 0, 0, 0);
      #pragma unroll
      for (int mt=0;mt<2;mt++)
        #pragma unroll
        for (int r=0;r<4;r++)
          lpa[mt][nt][r] = fmaf(s[mt][r], s[mt][r], lpa[mt][nt][r]);
    }
  }

  // epilogue; C/D layout: n = lane&15, m = quad*4 + reg
  #pragma unroll
  for (int nt=0;nt<4;nt++){
    const int n = n0 + wc*64 + nt*16 + l16;
    const float bv = pbias[n];
    #pragma unroll
    for (int mt=0;mt<2;mt++){
      const int mb = m0 + wr*32 + mt*16 + quad*4;
      #pragma unroll
      for (int r=0;r<4;r++){
        float v = acc[mt][nt][r] + sqrtf(lpa[mt][nt][r]) + bv;
        v = (v > 0.f ? v : 0.f) - bv;
        y0[(size_t)(mb+r)*D_SZ + n] = f2b(v);
      }
    }
  }
}

// ---------------- m97-style BT GEMM (+LDS swizzle +XCD swizzle): C = A*Bm^T.
// DO_STATS: stats over v = acc + bias[n] (fp32), atomically accumulated.
// CENTER: store acc (pre-bias, signal-sized) as bf16; bnfin folds bias back.
template<int DO_STATS, int CENTER, typename CT>
__global__ __launch_bounds__(256) void gemm_bt(
    const u16* __restrict__ A, const u16* __restrict__ Bm,
    CT* __restrict__ C, const float* __restrict__ bias,
    float* __restrict__ S1, float* __restrict__ S2,
    int nblog2, int N, int K)
{
  __shared__ __align__(16) u16 As[128*64];
  __shared__ __align__(16) u16 Bs[128*64];
  const int tid  = threadIdx.x;
  const int wave = tid >> 6, lane = tid & 63;
  const int quad = lane >> 4, l16 = lane & 15;
  int bx, by;  swz(blockIdx.x, nblog2, bx, by);
  const int n0 = bx * 128, m0 = by * 128;
  const int wr = wave >> 1, wc = wave & 1;
  const int lr  = lane >> 3;
  const int lcs = (((lane & 7) ^ lr)) * 8;
  const int sw  = (l16 & 7);

  f32x4v acc[4][4];
  #pragma unroll
  for (int i=0;i<4;i++)
    #pragma unroll
    for (int j=0;j<4;j++)
      acc[i][j] = (f32x4v){0.f,0.f,0.f,0.f};

  for (int k0 = 0; k0 < K; k0 += 64){
    __syncthreads();
    #pragma unroll
    for (int c=0;c<4;c++){
      const int r0 = wave*32 + 8*c;          // 8 rows per 16B-call
      gload16(A  + (size_t)(m0 + r0 + lr)*K + k0 + lcs, As + r0*64);
      gload16(Bm + (size_t)(n0 + r0 + lr)*K + k0 + lcs, Bs + r0*64);
    }
    __syncthreads();
    #pragma unroll
    for (int ks=0; ks<2; ks++){
      bf16x8v af[4], bfr[4];
      #pragma unroll
      for (int mt=0;mt<4;mt++)
        af[mt] = *(const bf16x8v*)&As[(wr*64+mt*16+l16)*64 + (((ks*4+quad) ^ sw))*8];
      #pragma unroll
      for (int nt=0;nt<4;nt++)
        bfr[nt] = *(const bf16x8v*)&Bs[(wc*64+nt*16+l16)*64 + (((ks*4+quad) ^ sw))*8];
      #pragma unroll
      for (int mt=0;mt<4;mt++)
        #pragma unroll
        for (int nt=0;nt<4;nt++)
          acc[mt][nt] = __builtin_amdgcn_mfma_f32_16x16x32_bf16(af[mt], bfr[nt], acc[mt][nt], 0, 0, 0);
    }
  }

  // epilogue; C/D layout: n = lane&15, m = quad*4 + reg
  #pragma unroll
  for (int nt=0;nt<4;nt++){
    const int n = n0 + wc*64 + nt*16 + l16;
    float bv = 0.f;
    if (DO_STATS) bv = bias[n];
    float ls1 = 0.f, ls2 = 0.f;
    #pragma unroll
    for (int mt=0;mt<4;mt++){
      const int mb = m0 + wr*64 + mt*16 + quad*4;
      #pragma unroll
      for (int r=0;r<4;r++){
        float v = acc[mt][nt][r] + bv;
        if constexpr (sizeof(CT) == 2) C[(size_t)(mb+r)*N + n] = f2b(CENTER ? acc[mt][nt][r] : v);
        else                           C[(size_t)(mb+r)*N + n] = v;
        ls1 += v; ls2 += v*v;
      }
    }
    if (DO_STATS){
      ls1 += __shfl_xor(ls1, 16); ls2 += __shfl_xor(ls2, 16);
      ls1 += __shfl_xor(ls1, 32); ls2 += __shfl_xor(ls2, 32);
      if (quad == 0){ atomicAdd(&S1[n], ls1); atomicAdd(&S2[n], ls2); }
    }
  }
}

// ---------------- BN finalize: per-column scale/offset; folds the centered
// bias back: stored z is (z_full - cadd), so Bout = bnof - m*a + a*cadd.
__global__ void k_bnfin(const float* __restrict__ S1, const float* __restrict__ S2, int n,
                        const float* __restrict__ bnsc, const float* __restrict__ bnof,
                        const float* __restrict__ cadd,
                        float* __restrict__ Aout, float* __restrict__ Bout)
{
  int i = blockIdx.x*256 + threadIdx.x;
  if (i < n){
    const float invB = 1.f / 16384.f;
    float m   = S1[i]*invB;
    float var = S2[i]*invB - m*m;
    float a   = bnsc[0] * rsqrtf(var + 1e-10f);
    Aout[i] = a;
    Bout[i] = bnof[0] - m*a + a*cadd[i];
  }
}

// ---------------- BN apply + relu: bf16 centered Z in, bf16 Y out, 8/thread
__global__ __launch_bounds__(256) void k_bnapply(
    const u16* __restrict__ Z, u16* __restrict__ Y,
    const float* __restrict__ Aa, const float* __restrict__ Bb, int nmask)
{
  size_t base = ((size_t)blockIdx.x*256 + threadIdx.x) * 8;
  int n0 = (int)(base & (size_t)nmask);
  union { uint4 q; u16 s[8]; } z, o;
  z.q = *(const uint4*)&Z[base];
  #pragma unroll
  for (int j=0;j<8;j++){
    float v = b2f(z.s[j]) * Aa[n0+j] + Bb[n0+j];
    o.s[j] = f2b(v > 0.f ? v : 0.f);
  }
  *(uint4*)&Y[base] = o.q;
}

// ---------------- final: BN+relu on centered z2 fused with dot + sigmoid.
// One wave per row.
__global__ __launch_bounds__(256) void k_out(
    const u16* __restrict__ Z2, const float* __restrict__ wvec,
    const float* __restrict__ obp,
    const float* __restrict__ Aa, const float* __restrict__ Bb,
    float* __restrict__ out)
{
  const int wave = threadIdx.x >> 6, lane = threadIdx.x & 63;
  const int b = blockIdx.x*4 + wave;
  const int n0 = lane*8;
  union { uint4 q; u16 s[8]; } z;
  z.q = *(const uint4*)&Z2[(size_t)b*H2_SZ + n0];
  float4 wa = *(const float4*)&wvec[n0];
  float4 wb = *(const float4*)&wvec[n0+4];
  float wv[8] = {wa.x,wa.y,wa.z,wa.w,wb.x,wb.y,wb.z,wb.w};
  float s = 0.f;
  #pragma unroll
  for (int j=0;j<8;j++){
    float y = b2f(z.s[j]) * Aa[n0+j] + Bb[n0+j];
    y = y > 0.f ? y : 0.f;
    s += y * wv[j];
  }
  s += __shfl_xor(s,1);  s += __shfl_xor(s,2);  s += __shfl_xor(s,4);
  s += __shfl_xor(s,8);  s += __shfl_xor(s,16); s += __shfl_xor(s,32);
  if (lane == 0){
    float x = s + obp[0];
    out[b] = 1.f / (1.f + expf(-x));
  }
}

// ---------------- workspace map (bytes) ----------------
// embT @ 0          : 134217728   (dead after k_prod; reused:)
//   z1c @ 0         :  33554432   (bf16 centered pre-BN layer0)
//   y1  @ 67108864  :  33554432   (bf16 post-BN layer0)
//   z2c @ 100663296 :  16777216   (bf16 centered pre-BN layer1)
// WlT  @ 134217728  :   4194304   (dead after k_prod)
// y0   @ 138412032  :  16777216   (bf16, bias-centered)
// W0T  @ 155189248  :   1048576
// W1T  @ 156237824  :   1048576
// stats@ 174063616  : 16 KB ZEROED: S1a[1024] S2a[1024] S1b[512] S2b[512] cvec[1024]
//                     then A0[1024] B0[1024] A1[512] B1[512]
// pqT  @ 174096384  :     65536
// total ~ 174.2 MB

extern "C" void kernel_launch(void* const* d_in, const int* in_sizes, int n_in,
                              void* d_out, int out_size, void* d_ws, size_t ws_size,
                              hipStream_t stream)
{
  const int*   fidx  = (const int*)d_in[0];
  const float* fval  = (const float*)d_in[1];
  const float* femb  = (const float*)d_in[2];
  const float* wl    = (const float*)d_in[3];
  const float* pbias = (const float*)d_in[4];
  const float* pq    = (const float*)d_in[5];
  const float* w0    = (const float*)d_in[6];
  const float* b0    = (const float*)d_in[7];
  const float* w1    = (const float*)d_in[8];
  const float* b1    = (const float*)d_in[9];
  const float* bnsc  = (const float*)d_in[10];
  const float* bnof  = (const float*)d_in[11];
  const float* ow    = (const float*)d_in[12];
  const float* ob    = (const float*)d_in[13];
  float* out = (float*)d_out;

  char* ws = (char*)d_ws;
  u16*   embT = (u16*)(ws + 0);
  u16*   z1b  = (u16*)(ws + 0);
  u16*   y1b  = (u16*)(ws + 67108864);
  u16*   z2b  = (u16*)(ws + 100663296);
  u16*   wlT  = (u16*)(ws + 134217728);
  u16*   y0b  = (u16*)(ws + 138412032);
  u16*   w0T  = (u16*)(ws + 155189248);
  u16*   w1T  = (u16*)(ws + 156237824);
  float* S1a  = (float*)(ws + 174063616);
  float* S2a  = S1a + 1024;
  float* S1b  = S2a + 1024;
  float* S2b  = S1b + 512;
  float* cvec = S2b + 512;
  float* A0   = cvec + 1024;
  float* B0   = A0 + 1024;
  float* A1   = B0 + 1024;
  float* B1   = A1 + 512;
  u16*   pqT  = (u16*)(ws + 174096384);

  hipMemsetAsync((void*)S1a, 0, 16384, stream);      // S1a,S2a,S1b,S2b,cvec

  k_gather<<<B_SZ, 256, 0, stream>>>(fidx, fval, femb, embT);
  k_wlt<<<D_SZ, 256, 0, stream>>>(wl, wlT);
  k_pqt<<<128, 256, 0, stream>>>(pq, pqT);
  k_transpose<<<2048, 256, 0, stream>>>(w0, w0T, 9, 1024, 524288);   // (512,1024)->(1024,512)
  k_transpose<<<2048, 256, 0, stream>>>(w1, w1T, 10, 512, 524288);   // (1024,512)->(512,1024)
  k_cvec<<<dim3(4,8), 256, 0, stream>>>(pbias, w0, b0, cvec);

  k_prod<<<1024, 256, 0, stream>>>(embT, wlT, pqT, pbias, y0b);

  // layer 0: z1c (centered bf16) + batch stats
  gemm_bt<1,1,u16><<<1024, 256, 0, stream>>>(y0b, w0T, z1b, cvec, S1a, S2a,
                                             3, H1_SZ, D_SZ);
  k_bnfin<<<4, 256, 0, stream>>>(S1a, S2a, 1024, bnsc, bnof, cvec, A0, B0);
  k_bnapply<<<8192, 256, 0, stream>>>(z1b, y1b, A0, B0, 1023);

  // layer 1: z2c (centered bf16) + batch stats
  gemm_bt<1,1,u16><<<512, 256, 0, stream>>>(y1b, w1T, z2b, b1, S1b, S2b,
                                            2, H2_SZ, H1_SZ);
  k_bnfin<<<2, 256, 0, stream>>>(S1b, S2b, 512, bnsc, bnof, b1, A1, B1);

  k_out<<<4096, 256, 0, stream>>>(z2b, ow, ob, A1, B1, out);
}

// Round 12
// 399.883 us; speedup vs baseline: 1.5780x; 1.0170x over previous
//
#include <hip/hip_runtime.h>

typedef unsigned short u16;
typedef __attribute__((ext_vector_type(8))) short bf16x8v;
typedef __attribute__((ext_vector_type(4))) float f32x4v;

#define B_SZ 16384
#define F_SZ 50
#define E_SZ 64
#define D_SZ 512
#define H1_SZ 1024
#define H2_SZ 512
#define KP 4096   // padded product-layer K: (e*64+f), f padded 50->64

__device__ __forceinline__ float b2f(u16 u){
  union { unsigned int i; float f; } v; v.i = ((unsigned int)u) << 16; return v.f;
}
__device__ __forceinline__ u16 f2b(float f){
  union { float f; unsigned int i; } v; v.f = f;
  unsigned int r = v.i + 0x7FFFu + ((v.i >> 16) & 1u);
  return (u16)(r >> 16);
}

// async global->LDS, 16B/lane. g is per-lane (base + lane*16B); lds base is
// wave-uniform; HW writes lds_base + lane*16.
__device__ __forceinline__ void gload16(const u16* g, u16* lds_base_uniform){
#if __has_builtin(__builtin_amdgcn_global_load_lds)
  __builtin_amdgcn_global_load_lds(
      (const __attribute__((address_space(1))) unsigned int*)g,
      (__attribute__((address_space(3))) unsigned int*)lds_base_uniform,
      16, 0, 0);
#else
  int lane = threadIdx.x & 63;
  *(uint4*)(lds_base_uniform + lane*8) = *(const uint4*)g;
#endif
}

// XCD-aware grid swizzle (r11: verified FETCH 270->99 MB): blocks sharing an
// A(m)-tile get IDs equal mod 8 -> same XCD L2. x = n-tile, y = m-tile.
__device__ __forceinline__ void swz(int id, int nblog2, int &x, int &y){
  int xcd = id & 7, j = id >> 3;
  x = j & ((1 << nblog2) - 1);
  y = ((j >> nblog2) << 3) | xcd;
}

// ---------------- gather: embT[b][e*64+f] = fe[idx[b,f],e]*fv[b,f] (bf16), f>=50 -> 0
__global__ __launch_bounds__(256) void k_gather(
    const int* __restrict__ fidx, const float* __restrict__ fval,
    const float* __restrict__ femb, u16* __restrict__ embT)
{
  __shared__ int   sidx[F_SZ];
  __shared__ float sfv[F_SZ];
  __shared__ u16   tile[F_SZ*66];   // padded stride 66 to break bank conflicts
  const int b = blockIdx.x, t = threadIdx.x;
  if (t < F_SZ){ sidx[t] = fidx[b*F_SZ+t]; sfv[t] = fval[b*F_SZ+t]; }
  __syncthreads();
  #pragma unroll
  for (int i=0;i<13;i++){
    int k = i*256+t;
    if (k < F_SZ*E_SZ){
      int f = k>>6, e = k&63;
      tile[f*66+e] = f2b(femb[(size_t)sidx[f]*E_SZ + e] * sfv[f]);
    }
  }
  __syncthreads();
  u16* orow = embT + (size_t)b*KP;
  #pragma unroll
  for (int i=0;i<16;i++){
    int k = i*256+t;           // k = e*64+f
    int f = k&63, e = k>>6;
    orow[k] = (f < F_SZ) ? tile[f*66+e] : (u16)0;
  }
}

// ---------------- merged weight prep: one launch, ranged by blockIdx.
// [0,512)    : Wl (D,F,E) fp32 -> WlT (D, e*64+f) bf16 zero-padded
// [512,640)  : Pq (D,F) fp32 -> PqTp (D,64) bf16 padded
// [640,2688) : w0 (512,1024) fp32 -> w0T (1024,512) bf16
// [2688,4736): w1 (1024,512) fp32 -> w1T (512,1024) bf16
// [4736,4768): cvec[h] += sum_d pbias[d]*W0[d][h] (+ b0[h] once); pre-zeroed
__global__ __launch_bounds__(256) void k_prep(
    const float* __restrict__ Wl, u16* __restrict__ WlT,
    const float* __restrict__ Pq, u16* __restrict__ PqTp,
    const float* __restrict__ w0, u16* __restrict__ w0T,
    const float* __restrict__ w1, u16* __restrict__ w1T,
    const float* __restrict__ pb, const float* __restrict__ b0,
    float* __restrict__ cvec)
{
  __shared__ u16 tile[F_SZ*66];
  const int r = blockIdx.x, t = threadIdx.x;
  if (r < 512){
    const int d = r;
    #pragma unroll
    for (int i=0;i<13;i++){
      int k = i*256+t;
      if (k < F_SZ*E_SZ) tile[(k>>6)*66 + (k&63)] = f2b(Wl[(size_t)d*(F_SZ*E_SZ) + k]);
    }
    __syncthreads();
    u16* orow = WlT + (size_t)d*KP;
    #pragma unroll
    for (int i=0;i<16;i++){
      int k = i*256+t;
      int f = k&63, e = k>>6;
      orow[k] = (f < F_SZ) ? tile[f*66+e] : (u16)0;
    }
  } else if (r < 640){
    int idx = (r-512)*256 + t;          // 32768 slots
    int d = idx >> 6, f = idx & 63;
    PqTp[idx] = (f < F_SZ) ? f2b(Pq[d*F_SZ + f]) : (u16)0;
  } else if (r < 2688){
    int idx = (r-640)*256 + t;          // 524288
    int k = idx & 511, n = idx >> 9;
    w0T[idx] = f2b(w0[(size_t)k*H1_SZ + n]);
  } else if (r < 4736){
    int idx = (r-2688)*256 + t;         // 524288
    int k = idx & 1023, n = idx >> 10;
    w1T[idx] = f2b(w1[(size_t)k*H2_SZ + n]);
  } else {
    int rr = r - 4736;
    int h = (rr & 3)*256 + t;
    int d0 = (rr >> 2)*64;
    float acc = (d0 == 0) ? b0[h] : 0.f;
    #pragma unroll 8
    for (int d=0; d<64; d++) acc += pb[d0+d]*w0[(size_t)(d0+d)*H1_SZ + h];
    atomicAdd(&cvec[h], acc);
  }
}

// XOR-swizzled LDS tile layout (r9: SQ_LDS_BANK_CONFLICT -> 0): LDS slot
// (row, block j) holds global 8-elem column block (j XOR (row&7)); staged by
// fetching global block ((lane&7) XOR lr); fragments read ((Q XOR (l16&7))*8).

// ---------------- fused product layer v6 (unchanged from r11, at plateau):
// 256 threads, 64b x 128d tile, XCD-swizzled grid. One pass computes lz and lp.
__global__ __launch_bounds__(256) void k_prod(
    const u16* __restrict__ A,     // embT (B, KP)
    const u16* __restrict__ Bm,    // WlT  (D, KP)
    const u16* __restrict__ Pp,    // PqTp (D, 64)
    const float* __restrict__ pbias,
    u16* __restrict__ y0)          // (B, D)
{
  __shared__ __align__(16) u16 As[64*64];     // 8 KB
  __shared__ __align__(16) u16 Bs[128*64];    // 16 KB
  const int tid  = threadIdx.x;
  const int wave = tid >> 6, lane = tid & 63;
  const int quad = lane >> 4, l16 = lane & 15;
  int bx, by;  swz(blockIdx.x, 2, bx, by);    // 4 n-tiles, 256 m-tiles
  const int n0 = bx * 128, m0 = by * 64;
  const int wr = wave >> 1, wc = wave & 1;    // wr 0..1 (32 m-rows), wc 0..1 (64 n)
  const int lr  = lane >> 3;
  const int lcs = (((lane & 7) ^ lr)) * 8;    // swizzled global column block
  const int sw  = (l16 & 7);                  // fragment-read swizzle key

  bf16x8v pfr[4][2];
  #pragma unroll
  for (int nt=0;nt<4;nt++)
    #pragma unroll
    for (int ks=0;ks<2;ks++)
      pfr[nt][ks] = *(const bf16x8v*)&Pp[(n0 + wc*64 + nt*16 + l16)*64 + ks*32 + quad*8];

  f32x4v acc[2][4];
  f32x4v lpa[2][4];
  #pragma unroll
  for (int i=0;i<2;i++)
    #pragma unroll
    for (int j=0;j<4;j++){
      acc[i][j] = (f32x4v){0.f,0.f,0.f,0.f};
      lpa[i][j] = (f32x4v){0.f,0.f,0.f,0.f};
    }
  const f32x4v zz = {0.f,0.f,0.f,0.f};

  for (int k0 = 0; k0 < KP; k0 += 64){
    __syncthreads();
    #pragma unroll
    for (int c=0;c<2;c++){
      const int r0 = wave*16 + c*8;
      gload16(A + (size_t)(m0 + r0 + lr)*KP + k0 + lcs, As + r0*64);
    }
    #pragma unroll
    for (int c=0;c<4;c++){
      const int r0 = wave*32 + c*8;
      gload16(Bm + (size_t)(n0 + r0 + lr)*KP + k0 + lcs, Bs + r0*64);
    }
    __syncthreads();

    bf16x8v af[2][2];
    #pragma unroll
    for (int ks=0;ks<2;ks++)
      #pragma unroll
      for (int mt=0;mt<2;mt++)
        af[ks][mt] = *(const bf16x8v*)&As[(wr*32+mt*16+l16)*64 + (((ks*4+quad) ^ sw))*8];

    #pragma unroll
    for (int ks=0; ks<2; ks++){
      bf16x8v bfr[4];
      #pragma unroll
      for (int nt=0;nt<4;nt++)
        bfr[nt] = *(const bf16x8v*)&Bs[(wc*64+nt*16+l16)*64 + (((ks*4+quad) ^ sw))*8];
      #pragma unroll
      for (int mt=0;mt<2;mt++)
        #pragma unroll
        for (int nt=0;nt<4;nt++)
          acc[mt][nt] = __builtin_amdgcn_mfma_f32_16x16x32_bf16(af[ks][mt], bfr[nt], acc[mt][nt], 0, 0, 0);
    }

    #pragma unroll
    for (int nt=0;nt<4;nt++){
      f32x4v s[2];
      #pragma unroll
      for (int mt=0;mt<2;mt++)
        s[mt] = __builtin_amdgcn_mfma_f32_16x16x32_bf16(af[0][mt], pfr[nt][0], zz, 0, 0, 0);
      #pragma unroll
      for (int mt=0;mt<2;mt++)
        s[mt] = __builtin_amdgcn_mfma_f32_16x16x32_bf16(af[1][mt], pfr[nt][1], s[mt], 0, 0, 0);
      #pragma unroll
      for (int mt=0;mt<2;mt++)
        #pragma unroll
        for (int r=0;r<4;r++)
          lpa[mt][nt][r] = fmaf(s[mt][r], s[mt][r], lpa[mt][nt][r]);
    }
  }

  #pragma unroll
  for (int nt=0;nt<4;nt++){
    const int n = n0 + wc*64 + nt*16 + l16;
    const float bv = pbias[n];
    #pragma unroll
    for (int mt=0;mt<2;mt++){
      const int mb = m0 + wr*32 + mt*16 + quad*4;
      #pragma unroll
      for (int r=0;r<4;r++){
        float v = acc[mt][nt][r] + sqrtf(lpa[mt][nt][r]) + bv;
        v = (v > 0.f ? v : 0.f) - bv;
        y0[(size_t)(mb+r)*D_SZ + n] = f2b(v);
      }
    }
  }
}

// ---------------- BT GEMM v2: 64m x 128n tile, 256 threads (k_prod v5 recipe:
// 24 KB LDS, small acc -> more resident blocks). +LDS swizzle +XCD swizzle.
// DO_STATS: stats over v = acc + bias[n] (fp32), atomically accumulated.
// CENTER: store acc (pre-bias, signal-sized) as bf16; bnfin folds bias back.
template<int DO_STATS, int CENTER, typename CT>
__global__ __launch_bounds__(256) void gemm_bt(
    const u16* __restrict__ A, const u16* __restrict__ Bm,
    CT* __restrict__ C, const float* __restrict__ bias,
    float* __restrict__ S1, float* __restrict__ S2,
    int nblog2, int N, int K)
{
  __shared__ __align__(16) u16 As[64*64];     // 8 KB
  __shared__ __align__(16) u16 Bs[128*64];    // 16 KB
  const int tid  = threadIdx.x;
  const int wave = tid >> 6, lane = tid & 63;
  const int quad = lane >> 4, l16 = lane & 15;
  int bx, by;  swz(blockIdx.x, nblog2, bx, by);
  const int n0 = bx * 128, m0 = by * 64;
  const int wr = wave >> 1, wc = wave & 1;
  const int lr  = lane >> 3;
  const int lcs = (((lane & 7) ^ lr)) * 8;
  const int sw  = (l16 & 7);

  f32x4v acc[2][4];
  #pragma unroll
  for (int i=0;i<2;i++)
    #pragma unroll
    for (int j=0;j<4;j++)
      acc[i][j] = (f32x4v){0.f,0.f,0.f,0.f};

  for (int k0 = 0; k0 < K; k0 += 64){
    __syncthreads();
    #pragma unroll
    for (int c=0;c<2;c++){
      const int r0 = wave*16 + c*8;
      gload16(A + (size_t)(m0 + r0 + lr)*K + k0 + lcs, As + r0*64);
    }
    #pragma unroll
    for (int c=0;c<4;c++){
      const int r0 = wave*32 + c*8;
      gload16(Bm + (size_t)(n0 + r0 + lr)*K + k0 + lcs, Bs + r0*64);
    }
    __syncthreads();
    #pragma unroll
    for (int ks=0; ks<2; ks++){
      bf16x8v af[2], bfr[4];
      #pragma unroll
      for (int mt=0;mt<2;mt++)
        af[mt] = *(const bf16x8v*)&As[(wr*32+mt*16+l16)*64 + (((ks*4+quad) ^ sw))*8];
      #pragma unroll
      for (int nt=0;nt<4;nt++)
        bfr[nt] = *(const bf16x8v*)&Bs[(wc*64+nt*16+l16)*64 + (((ks*4+quad) ^ sw))*8];
      #pragma unroll
      for (int mt=0;mt<2;mt++)
        #pragma unroll
        for (int nt=0;nt<4;nt++)
          acc[mt][nt] = __builtin_amdgcn_mfma_f32_16x16x32_bf16(af[mt], bfr[nt], acc[mt][nt], 0, 0, 0);
    }
  }

  // epilogue; C/D layout: n = lane&15, m = quad*4 + reg
  #pragma unroll
  for (int nt=0;nt<4;nt++){
    const int n = n0 + wc*64 + nt*16 + l16;
    float bv = 0.f;
    if (DO_STATS) bv = bias[n];
    float ls1 = 0.f, ls2 = 0.f;
    #pragma unroll
    for (int mt=0;mt<2;mt++){
      const int mb = m0 + wr*32 + mt*16 + quad*4;
      #pragma unroll
      for (int r=0;r<4;r++){
        float v = acc[mt][nt][r] + bv;
        if constexpr (sizeof(CT) == 2) C[(size_t)(mb+r)*N + n] = f2b(CENTER ? acc[mt][nt][r] : v);
        else                           C[(size_t)(mb+r)*N + n] = v;
        ls1 += v; ls2 += v*v;
      }
    }
    if (DO_STATS){
      ls1 += __shfl_xor(ls1, 16); ls2 += __shfl_xor(ls2, 16);
      ls1 += __shfl_xor(ls1, 32); ls2 += __shfl_xor(ls2, 32);
      if (quad == 0){ atomicAdd(&S1[n], ls1); atomicAdd(&S2[n], ls2); }
    }
  }
}

// ---------------- BN finalize: per-column scale/offset; folds the centered
// bias back: stored z is (z_full - cadd), so Bout = bnof - m*a + a*cadd.
__global__ void k_bnfin(const float* __restrict__ S1, const float* __restrict__ S2, int n,
                        const float* __restrict__ bnsc, const float* __restrict__ bnof,
                        const float* __restrict__ cadd,
                        float* __restrict__ Aout, float* __restrict__ Bout)
{
  int i = blockIdx.x*256 + threadIdx.x;
  if (i < n){
    const float invB = 1.f / 16384.f;
    float m   = S1[i]*invB;
    float var = S2[i]*invB - m*m;
    float a   = bnsc[0] * rsqrtf(var + 1e-10f);
    Aout[i] = a;
    Bout[i] = bnof[0] - m*a + a*cadd[i];
  }
}

// ---------------- BN apply + relu: bf16 centered Z in, bf16 Y out, 8/thread
__global__ __launch_bounds__(256) void k_bnapply(
    const u16* __restrict__ Z, u16* __restrict__ Y,
    const float* __restrict__ Aa, const float* __restrict__ Bb, int nmask)
{
  size_t base = ((size_t)blockIdx.x*256 + threadIdx.x) * 8;
  int n0 = (int)(base & (size_t)nmask);
  union { uint4 q; u16 s[8]; } z, o;
  z.q = *(const uint4*)&Z[base];
  #pragma unroll
  for (int j=0;j<8;j++){
    float v = b2f(z.s[j]) * Aa[n0+j] + Bb[n0+j];
    o.s[j] = f2b(v > 0.f ? v : 0.f);
  }
  *(uint4*)&Y[base] = o.q;
}

// ---------------- final: BN+relu on centered z2 fused with dot + sigmoid.
__global__ __launch_bounds__(256) void k_out(
    const u16* __restrict__ Z2, const float* __restrict__ wvec,
    const float* __restrict__ obp,
    const float* __restrict__ Aa, const float* __restrict__ Bb,
    float* __restrict__ out)
{
  const int wave = threadIdx.x >> 6, lane = threadIdx.x & 63;
  const int b = blockIdx.x*4 + wave;
  const int n0 = lane*8;
  union { uint4 q; u16 s[8]; } z;
  z.q = *(const uint4*)&Z2[(size_t)b*H2_SZ + n0];
  float4 wa = *(const float4*)&wvec[n0];
  float4 wb = *(const float4*)&wvec[n0+4];
  float wv[8] = {wa.x,wa.y,wa.z,wa.w,wb.x,wb.y,wb.z,wb.w};
  float s = 0.f;
  #pragma unroll
  for (int j=0;j<8;j++){
    float y = b2f(z.s[j]) * Aa[n0+j] + Bb[n0+j];
    y = y > 0.f ? y : 0.f;
    s += y * wv[j];
  }
  s += __shfl_xor(s,1);  s += __shfl_xor(s,2);  s += __shfl_xor(s,4);
  s += __shfl_xor(s,8);  s += __shfl_xor(s,16); s += __shfl_xor(s,32);
  if (lane == 0){
    float x = s + obp[0];
    out[b] = 1.f / (1.f + expf(-x));
  }
}

// ---------------- workspace map (bytes) ----------------
// embT @ 0          : 134217728   (dead after k_prod; reused:)
//   z1c @ 0         :  33554432   (bf16 centered pre-BN layer0)
//   y1  @ 67108864  :  33554432   (bf16 post-BN layer0)
//   z2c @ 100663296 :  16777216   (bf16 centered pre-BN layer1)
// WlT  @ 134217728  :   4194304   (dead after k_prod)
// y0   @ 138412032  :  16777216   (bf16, bias-centered)
// W0T  @ 155189248  :   1048576
// W1T  @ 156237824  :   1048576
// stats@ 174063616  : 16 KB ZEROED: S1a[1024] S2a[1024] S1b[512] S2b[512] cvec[1024]
//                     then A0[1024] B0[1024] A1[512] B1[512]
// pqT  @ 174096384  :     65536
// total ~ 174.2 MB

extern "C" void kernel_launch(void* const* d_in, const int* in_sizes, int n_in,
                              void* d_out, int out_size, void* d_ws, size_t ws_size,
                              hipStream_t stream)
{
  const int*   fidx  = (const int*)d_in[0];
  const float* fval  = (const float*)d_in[1];
  const float* femb  = (const float*)d_in[2];
  const float* wl    = (const float*)d_in[3];
  const float* pbias = (const float*)d_in[4];
  const float* pq    = (const float*)d_in[5];
  const float* w0    = (const float*)d_in[6];
  const float* b0    = (const float*)d_in[7];
  const float* w1    = (const float*)d_in[8];
  const float* b1    = (const float*)d_in[9];
  const float* bnsc  = (const float*)d_in[10];
  const float* bnof  = (const float*)d_in[11];
  const float* ow    = (const float*)d_in[12];
  const float* ob    = (const float*)d_in[13];
  float* out = (float*)d_out;

  char* ws = (char*)d_ws;
  u16*   embT = (u16*)(ws + 0);
  u16*   z1b  = (u16*)(ws + 0);
  u16*   y1b  = (u16*)(ws + 67108864);
  u16*   z2b  = (u16*)(ws + 100663296);
  u16*   wlT  = (u16*)(ws + 134217728);
  u16*   y0b  = (u16*)(ws + 138412032);
  u16*   w0T  = (u16*)(ws + 155189248);
  u16*   w1T  = (u16*)(ws + 156237824);
  float* S1a  = (float*)(ws + 174063616);
  float* S2a  = S1a + 1024;
  float* S1b  = S2a + 1024;
  float* S2b  = S1b + 512;
  float* cvec = S2b + 512;
  float* A0   = cvec + 1024;
  float* B0   = A0 + 1024;
  float* A1   = B0 + 1024;
  float* B1   = A1 + 512;
  u16*   pqT  = (u16*)(ws + 174096384);

  hipMemsetAsync((void*)S1a, 0, 16384, stream);      // S1a,S2a,S1b,S2b,cvec

  k_gather<<<B_SZ, 256, 0, stream>>>(fidx, fval, femb, embT);
  k_prep<<<4768, 256, 0, stream>>>(wl, wlT, pq, pqT, w0, w0T, w1, w1T,
                                   pbias, b0, cvec);

  k_prod<<<1024, 256, 0, stream>>>(embT, wlT, pqT, pbias, y0b);

  // layer 0: z1c (centered bf16) + batch stats; 2048 blocks (8 n-tiles)
  gemm_bt<1,1,u16><<<2048, 256, 0, stream>>>(y0b, w0T, z1b, cvec, S1a, S2a,
                                             3, H1_SZ, D_SZ);
  k_bnfin<<<4, 256, 0, stream>>>(S1a, S2a, 1024, bnsc, bnof, cvec, A0, B0);
  k_bnapply<<<8192, 256, 0, stream>>>(z1b, y1b, A0, B0, 1023);

  // layer 1: z2c (centered bf16) + batch stats; 1024 blocks (4 n-tiles)
  gemm_bt<1,1,u16><<<1024, 256, 0, stream>>>(y1b, w1T, z2b, b1, S1b, S2b,
                                             2, H2_SZ, H1_SZ);
  k_bnfin<<<2, 256, 0, stream>>>(S1b, S2b, 512, bnsc, bnof, b1, A1, B1);

  k_out<<<4096, 256, 0, stream>>>(z2b, ow, ob, A1, B1, out);
}

// Round 13
// 391.191 us; speedup vs baseline: 1.6131x; 1.0222x over previous
//
#include <hip/hip_runtime.h>

typedef unsigned short u16;
typedef __attribute__((ext_vector_type(8))) short bf16x8v;
typedef __attribute__((ext_vector_type(4))) float f32x4v;

#define B_SZ 16384
#define F_SZ 50
#define E_SZ 64
#define D_SZ 512
#define H1_SZ 1024
#define H2_SZ 512
#define KP 4096   // padded product-layer K: (e*64+f), f padded 50->64

__device__ __forceinline__ float b2f(u16 u){
  union { unsigned int i; float f; } v; v.i = ((unsigned int)u) << 16; return v.f;
}
__device__ __forceinline__ u16 f2b(float f){
  union { float f; unsigned int i; } v; v.f = f;
  unsigned int r = v.i + 0x7FFFu + ((v.i >> 16) & 1u);
  return (u16)(r >> 16);
}

// async global->LDS, 16B/lane. g is per-lane (base + lane*16B); lds base is
// wave-uniform; HW writes lds_base + lane*16.
__device__ __forceinline__ void gload16(const u16* g, u16* lds_base_uniform){
#if __has_builtin(__builtin_amdgcn_global_load_lds)
  __builtin_amdgcn_global_load_lds(
      (const __attribute__((address_space(1))) unsigned int*)g,
      (__attribute__((address_space(3))) unsigned int*)lds_base_uniform,
      16, 0, 0);
#else
  int lane = threadIdx.x & 63;
  *(uint4*)(lds_base_uniform + lane*8) = *(const uint4*)g;
#endif
}

// XCD-aware grid swizzle (r11: verified FETCH 270->99 MB): blocks sharing an
// A(m)-tile get IDs equal mod 8 -> same XCD L2. x = n-tile, y = m-tile.
__device__ __forceinline__ void swz(int id, int nblog2, int &x, int &y){
  int xcd = id & 7, j = id >> 3;
  x = j & ((1 << nblog2) - 1);
  y = ((j >> nblog2) << 3) | xcd;
}

// ---------------- gather: embT[b][e*64+f] = fe[idx[b,f],e]*fv[b,f] (bf16), f>=50 -> 0
__global__ __launch_bounds__(256) void k_gather(
    const int* __restrict__ fidx, const float* __restrict__ fval,
    const float* __restrict__ femb, u16* __restrict__ embT)
{
  __shared__ int   sidx[F_SZ];
  __shared__ float sfv[F_SZ];
  __shared__ u16   tile[F_SZ*66];   // padded stride 66 to break bank conflicts
  const int b = blockIdx.x, t = threadIdx.x;
  if (t < F_SZ){ sidx[t] = fidx[b*F_SZ+t]; sfv[t] = fval[b*F_SZ+t]; }
  __syncthreads();
  #pragma unroll
  for (int i=0;i<13;i++){
    int k = i*256+t;
    if (k < F_SZ*E_SZ){
      int f = k>>6, e = k&63;
      tile[f*66+e] = f2b(femb[(size_t)sidx[f]*E_SZ + e] * sfv[f]);
    }
  }
  __syncthreads();
  u16* orow = embT + (size_t)b*KP;
  #pragma unroll
  for (int i=0;i<16;i++){
    int k = i*256+t;           // k = e*64+f
    int f = k&63, e = k>>6;
    orow[k] = (f < F_SZ) ? tile[f*66+e] : (u16)0;
  }
}

// ---------------- merged weight prep (r12): one launch, ranged by blockIdx.
__global__ __launch_bounds__(256) void k_prep(
    const float* __restrict__ Wl, u16* __restrict__ WlT,
    const float* __restrict__ Pq, u16* __restrict__ PqTp,
    const float* __restrict__ w0, u16* __restrict__ w0T,
    const float* __restrict__ w1, u16* __restrict__ w1T,
    const float* __restrict__ pb, const float* __restrict__ b0,
    float* __restrict__ cvec)
{
  __shared__ u16 tile[F_SZ*66];
  const int r = blockIdx.x, t = threadIdx.x;
  if (r < 512){
    const int d = r;
    #pragma unroll
    for (int i=0;i<13;i++){
      int k = i*256+t;
      if (k < F_SZ*E_SZ) tile[(k>>6)*66 + (k&63)] = f2b(Wl[(size_t)d*(F_SZ*E_SZ) + k]);
    }
    __syncthreads();
    u16* orow = WlT + (size_t)d*KP;
    #pragma unroll
    for (int i=0;i<16;i++){
      int k = i*256+t;
      int f = k&63, e = k>>6;
      orow[k] = (f < F_SZ) ? tile[f*66+e] : (u16)0;
    }
  } else if (r < 640){
    int idx = (r-512)*256 + t;          // 32768 slots
    int d = idx >> 6, f = idx & 63;
    PqTp[idx] = (f < F_SZ) ? f2b(Pq[d*F_SZ + f]) : (u16)0;
  } else if (r < 2688){
    int idx = (r-640)*256 + t;          // 524288
    int k = idx & 511, n = idx >> 9;
    w0T[idx] = f2b(w0[(size_t)k*H1_SZ + n]);
  } else if (r < 4736){
    int idx = (r-2688)*256 + t;         // 524288
    int k = idx & 1023, n = idx >> 10;
    w1T[idx] = f2b(w1[(size_t)k*H2_SZ + n]);
  } else {
    int rr = r - 4736;
    int h = (rr & 3)*256 + t;
    int d0 = (rr >> 2)*64;
    float acc = (d0 == 0) ? b0[h] : 0.f;
    #pragma unroll 8
    for (int d=0; d<64; d++) acc += pb[d0+d]*w0[(size_t)(d0+d)*H1_SZ + h];
    atomicAdd(&cvec[h], acc);
  }
}

// BK=128 XOR-swizzled LDS tiles: rows are 256 B (bank-degenerate); LDS slot
// (row, block j∈[0,16)) holds global 8-elem block (j XOR (row&7)). Staged by
// lane fetching global block ((lane&15) XOR (row&7)) (4 rows/call, lr4=lane>>4);
// fragments read offset ((ks*4+quad) XOR (l16&7))*8. Conflict-free (8-coset).

// ---------------- fused product layer v7: BK=128 (2 e-slices per barrier).
// 256 threads, 64b x 128d tile, 48 KB LDS (3 blocks/CU), XCD-swizzled grid.
__global__ __launch_bounds__(256) void k_prod(
    const u16* __restrict__ A,     // embT (B, KP)
    const u16* __restrict__ Bm,    // WlT  (D, KP)
    const u16* __restrict__ Pp,    // PqTp (D, 64)
    const float* __restrict__ pbias,
    u16* __restrict__ y0)          // (B, D)
{
  __shared__ __align__(16) u16 As[64*128];    // 16 KB
  __shared__ __align__(16) u16 Bs[128*128];   // 32 KB
  const int tid  = threadIdx.x;
  const int wave = tid >> 6, lane = tid & 63;
  const int quad = lane >> 4, l16 = lane & 15;
  int bx, by;  swz(blockIdx.x, 2, bx, by);    // 4 n-tiles, 256 m-tiles
  const int n0 = bx * 128, m0 = by * 64;
  const int wr = wave >> 1, wc = wave & 1;    // wr 0..1 (32 m-rows), wc 0..1 (64 n)
  const int lr4 = lane >> 4;                  // 4 rows per 16B-call
  const int cb  = lane & 15;                  // column block 0..15
  const int sw  = (l16 & 7);                  // fragment-read swizzle key

  bf16x8v pfr[4][2];
  #pragma unroll
  for (int nt=0;nt<4;nt++)
    #pragma unroll
    for (int ks=0;ks<2;ks++)
      pfr[nt][ks] = *(const bf16x8v*)&Pp[(n0 + wc*64 + nt*16 + l16)*64 + ks*32 + quad*8];

  f32x4v acc[2][4];
  f32x4v lpa[2][4];
  #pragma unroll
  for (int i=0;i<2;i++)
    #pragma unroll
    for (int j=0;j<4;j++){
      acc[i][j] = (f32x4v){0.f,0.f,0.f,0.f};
      lpa[i][j] = (f32x4v){0.f,0.f,0.f,0.f};
    }
  const f32x4v zz = {0.f,0.f,0.f,0.f};

  for (int k0 = 0; k0 < KP; k0 += 128){
    __syncthreads();
    // As: 64x128 = 16 calls (4/wave, 4 rows each); Bs: 128x128 = 32 calls (8/wave)
    #pragma unroll
    for (int c=0;c<4;c++){
      const int r0 = wave*16 + c*4;
      const int row = r0 + lr4;
      gload16(A + (size_t)(m0 + row)*KP + k0 + ((cb ^ (row & 7)) << 3), As + r0*128);
    }
    #pragma unroll
    for (int c=0;c<8;c++){
      const int r0 = wave*32 + c*4;
      const int row = r0 + lr4;
      gload16(Bm + (size_t)(n0 + row)*KP + k0 + ((cb ^ (row & 7)) << 3), Bs + r0*128);
    }
    __syncthreads();

    bf16x8v af[4][2];
    #pragma unroll
    for (int ks=0;ks<4;ks++)
      #pragma unroll
      for (int mt=0;mt<2;mt++)
        af[ks][mt] = *(const bf16x8v*)&As[(wr*32+mt*16+l16)*128 + (((ks*4+quad) ^ sw))*8];

    // lz: 32 MFMA over the 128-wide chunk
    #pragma unroll
    for (int ks=0; ks<4; ks++){
      bf16x8v bfr[4];
      #pragma unroll
      for (int nt=0;nt<4;nt++)
        bfr[nt] = *(const bf16x8v*)&Bs[(wc*64+nt*16+l16)*128 + (((ks*4+quad) ^ sw))*8];
      #pragma unroll
      for (int mt=0;mt<2;mt++)
        #pragma unroll
        for (int nt=0;nt<4;nt++)
          acc[mt][nt] = __builtin_amdgcn_mfma_f32_16x16x32_bf16(af[ks][mt], bfr[nt], acc[mt][nt], 0, 0, 0);
    }

    // lp: two e-slices per chunk, each K=64 vs register-resident pfr
    #pragma unroll
    for (int h=0; h<2; h++){
      #pragma unroll
      for (int nt=0;nt<4;nt++){
        f32x4v s[2];
        #pragma unroll
        for (int mt=0;mt<2;mt++)
          s[mt] = __builtin_amdgcn_mfma_f32_16x16x32_bf16(af[2*h][mt],   pfr[nt][0], zz,    0, 0, 0);
        #pragma unroll
        for (int mt=0;mt<2;mt++)
          s[mt] = __builtin_amdgcn_mfma_f32_16x16x32_bf16(af[2*h+1][mt], pfr[nt][1], s[mt], 0, 0, 0);
        #pragma unroll
        for (int mt=0;mt<2;mt++)
          #pragma unroll
          for (int r=0;r<4;r++)
            lpa[mt][nt][r] = fmaf(s[mt][r], s[mt][r], lpa[mt][nt][r]);
      }
    }
  }

  #pragma unroll
  for (int nt=0;nt<4;nt++){
    const int n = n0 + wc*64 + nt*16 + l16;
    const float bv = pbias[n];
    #pragma unroll
    for (int mt=0;mt<2;mt++){
      const int mb = m0 + wr*32 + mt*16 + quad*4;
      #pragma unroll
      for (int r=0;r<4;r++){
        float v = acc[mt][nt][r] + sqrtf(lpa[mt][nt][r]) + bv;
        v = (v > 0.f ? v : 0.f) - bv;
        y0[(size_t)(mb+r)*D_SZ + n] = f2b(v);
      }
    }
  }
}

// ---------------- BT GEMM v3: BK=128, 64m x 128n, 256 threads, 48 KB LDS.
// +LDS swizzle +XCD swizzle. DO_STATS: stats over v = acc + bias[n] (fp32).
// CENTER: store acc (pre-bias) as bf16; bnfin folds bias back.
template<int DO_STATS, int CENTER, typename CT>
__global__ __launch_bounds__(256) void gemm_bt(
    const u16* __restrict__ A, const u16* __restrict__ Bm,
    CT* __restrict__ C, const float* __restrict__ bias,
    float* __restrict__ S1, float* __restrict__ S2,
    int nblog2, int N, int K)
{
  __shared__ __align__(16) u16 As[64*128];    // 16 KB
  __shared__ __align__(16) u16 Bs[128*128];   // 32 KB
  const int tid  = threadIdx.x;
  const int wave = tid >> 6, lane = tid & 63;
  const int quad = lane >> 4, l16 = lane & 15;
  int bx, by;  swz(blockIdx.x, nblog2, bx, by);
  const int n0 = bx * 128, m0 = by * 64;
  const int wr = wave >> 1, wc = wave & 1;
  const int lr4 = lane >> 4;
  const int cb  = lane & 15;
  const int sw  = (l16 & 7);

  f32x4v acc[2][4];
  #pragma unroll
  for (int i=0;i<2;i++)
    #pragma unroll
    for (int j=0;j<4;j++)
      acc[i][j] = (f32x4v){0.f,0.f,0.f,0.f};

  for (int k0 = 0; k0 < K; k0 += 128){
    __syncthreads();
    #pragma unroll
    for (int c=0;c<4;c++){
      const int r0 = wave*16 + c*4;
      const int row = r0 + lr4;
      gload16(A + (size_t)(m0 + row)*K + k0 + ((cb ^ (row & 7)) << 3), As + r0*128);
    }
    #pragma unroll
    for (int c=0;c<8;c++){
      const int r0 = wave*32 + c*4;
      const int row = r0 + lr4;
      gload16(Bm + (size_t)(n0 + row)*K + k0 + ((cb ^ (row & 7)) << 3), Bs + r0*128);
    }
    __syncthreads();
    #pragma unroll
    for (int ks=0; ks<4; ks++){
      bf16x8v af[2], bfr[4];
      #pragma unroll
      for (int mt=0;mt<2;mt++)
        af[mt] = *(const bf16x8v*)&As[(wr*32+mt*16+l16)*128 + (((ks*4+quad) ^ sw))*8];
      #pragma unroll
      for (int nt=0;nt<4;nt++)
        bfr[nt] = *(const bf16x8v*)&Bs[(wc*64+nt*16+l16)*128 + (((ks*4+quad) ^ sw))*8];
      #pragma unroll
      for (int mt=0;mt<2;mt++)
        #pragma unroll
        for (int nt=0;nt<4;nt++)
          acc[mt][nt] = __builtin_amdgcn_mfma_f32_16x16x32_bf16(af[mt], bfr[nt], acc[mt][nt], 0, 0, 0);
    }
  }

  // epilogue; C/D layout: n = lane&15, m = quad*4 + reg
  #pragma unroll
  for (int nt=0;nt<4;nt++){
    const int n = n0 + wc*64 + nt*16 + l16;
    float bv = 0.f;
    if (DO_STATS) bv = bias[n];
    float ls1 = 0.f, ls2 = 0.f;
    #pragma unroll
    for (int mt=0;mt<2;mt++){
      const int mb = m0 + wr*32 + mt*16 + quad*4;
      #pragma unroll
      for (int r=0;r<4;r++){
        float v = acc[mt][nt][r] + bv;
        if constexpr (sizeof(CT) == 2) C[(size_t)(mb+r)*N + n] = f2b(CENTER ? acc[mt][nt][r] : v);
        else                           C[(size_t)(mb+r)*N + n] = v;
        ls1 += v; ls2 += v*v;
      }
    }
    if (DO_STATS){
      ls1 += __shfl_xor(ls1, 16); ls2 += __shfl_xor(ls2, 16);
      ls1 += __shfl_xor(ls1, 32); ls2 += __shfl_xor(ls2, 32);
      if (quad == 0){ atomicAdd(&S1[n], ls1); atomicAdd(&S2[n], ls2); }
    }
  }
}

// ---------------- BN finalize: per-column scale/offset; folds the centered
// bias back: stored z is (z_full - cadd), so Bout = bnof - m*a + a*cadd.
__global__ void k_bnfin(const float* __restrict__ S1, const float* __restrict__ S2, int n,
                        const float* __restrict__ bnsc, const float* __restrict__ bnof,
                        const float* __restrict__ cadd,
                        float* __restrict__ Aout, float* __restrict__ Bout)
{
  int i = blockIdx.x*256 + threadIdx.x;
  if (i < n){
    const float invB = 1.f / 16384.f;
    float m   = S1[i]*invB;
    float var = S2[i]*invB - m*m;
    float a   = bnsc[0] * rsqrtf(var + 1e-10f);
    Aout[i] = a;
    Bout[i] = bnof[0] - m*a + a*cadd[i];
  }
}

// ---------------- BN apply + relu: bf16 centered Z in, bf16 Y out, 8/thread
__global__ __launch_bounds__(256) void k_bnapply(
    const u16* __restrict__ Z, u16* __restrict__ Y,
    const float* __restrict__ Aa, const float* __restrict__ Bb, int nmask)
{
  size_t base = ((size_t)blockIdx.x*256 + threadIdx.x) * 8;
  int n0 = (int)(base & (size_t)nmask);
  union { uint4 q; u16 s[8]; } z, o;
  z.q = *(const uint4*)&Z[base];
  #pragma unroll
  for (int j=0;j<8;j++){
    float v = b2f(z.s[j]) * Aa[n0+j] + Bb[n0+j];
    o.s[j] = f2b(v > 0.f ? v : 0.f);
  }
  *(uint4*)&Y[base] = o.q;
}

// ---------------- final: BN+relu on centered z2 fused with dot + sigmoid.
__global__ __launch_bounds__(256) void k_out(
    const u16* __restrict__ Z2, const float* __restrict__ wvec,
    const float* __restrict__ obp,
    const float* __restrict__ Aa, const float* __restrict__ Bb,
    float* __restrict__ out)
{
  const int wave = threadIdx.x >> 6, lane = threadIdx.x & 63;
  const int b = blockIdx.x*4 + wave;
  const int n0 = lane*8;
  union { uint4 q; u16 s[8]; } z;
  z.q = *(const uint4*)&Z2[(size_t)b*H2_SZ + n0];
  float4 wa = *(const float4*)&wvec[n0];
  float4 wb = *(const float4*)&wvec[n0+4];
  float wv[8] = {wa.x,wa.y,wa.z,wa.w,wb.x,wb.y,wb.z,wb.w};
  float s = 0.f;
  #pragma unroll
  for (int j=0;j<8;j++){
    float y = b2f(z.s[j]) * Aa[n0+j] + Bb[n0+j];
    y = y > 0.f ? y : 0.f;
    s += y * wv[j];
  }
  s += __shfl_xor(s,1);  s += __shfl_xor(s,2);  s += __shfl_xor(s,4);
  s += __shfl_xor(s,8);  s += __shfl_xor(s,16); s += __shfl_xor(s,32);
  if (lane == 0){
    float x = s + obp[0];
    out[b] = 1.f / (1.f + expf(-x));
  }
}

// ---------------- workspace map (bytes) ----------------
// embT @ 0          : 134217728   (dead after k_prod; reused:)
//   z1c @ 0         :  33554432   (bf16 centered pre-BN layer0)
//   y1  @ 67108864  :  33554432   (bf16 post-BN layer0)
//   z2c @ 100663296 :  16777216   (bf16 centered pre-BN layer1)
// WlT  @ 134217728  :   4194304   (dead after k_prod)
// y0   @ 138412032  :  16777216   (bf16, bias-centered)
// W0T  @ 155189248  :   1048576
// W1T  @ 156237824  :   1048576
// stats@ 174063616  : 16 KB ZEROED: S1a[1024] S2a[1024] S1b[512] S2b[512] cvec[1024]
//                     then A0[1024] B0[1024] A1[512] B1[512]
// pqT  @ 174096384  :     65536
// total ~ 174.2 MB

extern "C" void kernel_launch(void* const* d_in, const int* in_sizes, int n_in,
                              void* d_out, int out_size, void* d_ws, size_t ws_size,
                              hipStream_t stream)
{
  const int*   fidx  = (const int*)d_in[0];
  const float* fval  = (const float*)d_in[1];
  const float* femb  = (const float*)d_in[2];
  const float* wl    = (const float*)d_in[3];
  const float* pbias = (const float*)d_in[4];
  const float* pq    = (const float*)d_in[5];
  const float* w0    = (const float*)d_in[6];
  const float* b0    = (const float*)d_in[7];
  const float* w1    = (const float*)d_in[8];
  const float* b1    = (const float*)d_in[9];
  const float* bnsc  = (const float*)d_in[10];
  const float* bnof  = (const float*)d_in[11];
  const float* ow    = (const float*)d_in[12];
  const float* ob    = (const float*)d_in[13];
  float* out = (float*)d_out;

  char* ws = (char*)d_ws;
  u16*   embT = (u16*)(ws + 0);
  u16*   z1b  = (u16*)(ws + 0);
  u16*   y1b  = (u16*)(ws + 67108864);
  u16*   z2b  = (u16*)(ws + 100663296);
  u16*   wlT  = (u16*)(ws + 134217728);
  u16*   y0b  = (u16*)(ws + 138412032);
  u16*   w0T  = (u16*)(ws + 155189248);
  u16*   w1T  = (u16*)(ws + 156237824);
  float* S1a  = (float*)(ws + 174063616);
  float* S2a  = S1a + 1024;
  float* S1b  = S2a + 1024;
  float* S2b  = S1b + 512;
  float* cvec = S2b + 512;
  float* A0   = cvec + 1024;
  float* B0   = A0 + 1024;
  float* A1   = B0 + 1024;
  float* B1   = A1 + 512;
  u16*   pqT  = (u16*)(ws + 174096384);

  hipMemsetAsync((void*)S1a, 0, 16384, stream);      // S1a,S2a,S1b,S2b,cvec

  k_gather<<<B_SZ, 256, 0, stream>>>(fidx, fval, femb, embT);
  k_prep<<<4768, 256, 0, stream>>>(wl, wlT, pq, pqT, w0, w0T, w1, w1T,
                                   pbias, b0, cvec);

  k_prod<<<1024, 256, 0, stream>>>(embT, wlT, pqT, pbias, y0b);

  // layer 0: z1c (centered bf16) + batch stats; 2048 blocks (8 n-tiles)
  gemm_bt<1,1,u16><<<2048, 256, 0, stream>>>(y0b, w0T, z1b, cvec, S1a, S2a,
                                             3, H1_SZ, D_SZ);
  k_bnfin<<<4, 256, 0, stream>>>(S1a, S2a, 1024, bnsc, bnof, cvec, A0, B0);
  k_bnapply<<<8192, 256, 0, stream>>>(z1b, y1b, A0, B0, 1023);

  // layer 1: z2c (centered bf16) + batch stats; 1024 blocks (4 n-tiles)
  gemm_bt<1,1,u16><<<1024, 256, 0, stream>>>(y1b, w1T, z2b, b1, S1b, S2b,
                                             2, H2_SZ, H1_SZ);
  k_bnfin<<<2, 256, 0, stream>>>(S1b, S2b, 512, bnsc, bnof, b1, A1, B1);

  k_out<<<4096, 256, 0, stream>>>(z2b, ow, ob, A1, B1, out);
}